// Round 4
// baseline (957.898 us; speedup 1.0000x reference)
//
#include <hip/hip_runtime.h>
#include <hip/hip_bf16.h>

using u16 = unsigned short;
typedef __bf16 bf16x8_t __attribute__((ext_vector_type(8)));
typedef float    f32x4  __attribute__((ext_vector_type(4)));
typedef unsigned short u16x8 __attribute__((ext_vector_type(8)));

#define B_  64
#define L_  1024
#define TOT 65536
#define D_  512
#define H_  2048
#define NH_ 8
#define NC_ 16   // l-chunks of 64 tokens for fused attention pass

__device__ __forceinline__ float b2f(u16 x) {
    union { unsigned int i; float f; } v; v.i = ((unsigned int)x) << 16; return v.f;
}
__device__ __forceinline__ u16 f2b(float f) {
    union { float f; unsigned int i; } v; v.f = f;
    unsigned int i = v.i;
    unsigned int r = i + 0x7FFFu + ((i >> 16) & 1u);   // RNE
    return (u16)(r >> 16);
}

// ---------------- transpose + fp32->bf16 convert:  in[R][C] f32 -> out[C][R] bf16
__global__ __launch_bounds__(256) void transpose_cvt(const float* __restrict__ in,
                                                     u16* __restrict__ out, int R, int C) {
    __shared__ float tile[32][33];
    int c0 = blockIdx.x * 32, r0 = blockIdx.y * 32;
    int tx = threadIdx.x, ty = threadIdx.y;
    #pragma unroll
    for (int i = 0; i < 4; ++i)
        tile[ty + 8 * i][tx] = in[(size_t)(r0 + ty + 8 * i) * C + c0 + tx];
    __syncthreads();
    #pragma unroll
    for (int i = 0; i < 4; ++i)
        out[(size_t)(c0 + ty + 8 * i) * R + r0 + tx] = f2b(tile[tx][ty + 8 * i]);
}

// ---------------- qp = q @ Wq + bq
__global__ __launch_bounds__(256) void qp_kernel(const float* __restrict__ q,
                                                 const float* __restrict__ Wq,
                                                 const float* __restrict__ bq,
                                                 float* __restrict__ qp) {
    __shared__ float qs[512];
    int tid = threadIdx.x;
    qs[tid] = q[tid]; qs[tid + 256] = q[tid + 256];
    __syncthreads();
    int j = blockIdx.x * 256 + tid;
    float acc = bq[j];
    #pragma unroll 8
    for (int d = 0; d < 512; ++d) acc += qs[d] * Wq[(size_t)d * 512 + j];
    qp[j] = acc;
}

// ---------------- wke[d][h] = 0.125*sum_j Wk[d,h*64+j]*qp[h*64+j];  cke[h] from bk
__global__ __launch_bounds__(256) void wke_kernel(const float* __restrict__ Wk,
                                                  const float* __restrict__ bk,
                                                  const float* __restrict__ qp,
                                                  float* __restrict__ wke,
                                                  float* __restrict__ cke) {
    __shared__ float qs[512];
    int tid = threadIdx.x;
    qs[tid] = qp[tid]; qs[tid + 256] = qp[tid + 256];
    __syncthreads();
    int d = blockIdx.x * 32 + (tid >> 3);
    int h = tid & 7;
    float s = 0.f;
    #pragma unroll 8
    for (int j = 0; j < 64; ++j) s += Wk[(size_t)d * 512 + h * 64 + j] * qs[h * 64 + j];
    wke[d * 8 + h] = 0.125f * s;
    if (blockIdx.x == 0 && tid < 8) {
        float c = 0.f;
        #pragma unroll 8
        for (int j = 0; j < 64; ++j) c += bk[tid * 64 + j] * qs[tid * 64 + j];
        cke[tid] = 0.125f * c;
    }
}

// ---------------- wv2t[h][k] = bf16( sum_d W2[k][d]*wke[d][h] ), rows 8..15 zero.
// ck2[h] = sum_d b2[d]*wke[d][h] + cke[h]
__global__ __launch_bounds__(256) void wv2_kernel(const float* __restrict__ W2,
                                                  const float* __restrict__ wke,
                                                  const float* __restrict__ cke,
                                                  const float* __restrict__ b2,
                                                  u16* __restrict__ wv2t,
                                                  float* __restrict__ ck2) {
    __shared__ float wk[512 * 8];
    int tid = threadIdx.x;
    for (int i = tid; i < 4096; i += 256) wk[i] = wke[i];
    __syncthreads();
    int k = blockIdx.x * 32 + (tid >> 3);
    int h = tid & 7;
    float s = 0.f;
    const float* row = W2 + (size_t)k * 512;
    #pragma unroll 8
    for (int d = 0; d < 512; ++d) s += row[d] * wk[d * 8 + h];
    wv2t[(size_t)h * 2048 + k] = f2b(s);
    wv2t[(size_t)(h + 8) * 2048 + k] = 0;
    if (blockIdx.x == 0 && tid < 8) {
        float c = 0.f;
        #pragma unroll 8
        for (int d = 0; d < 512; ++d) c += b2[d] * wk[d * 8 + tid];
        ck2[tid] = c + cke[tid];
    }
}

// ---------------- cvv[e] = sum_d b2[d]*Wv[d][e] + bv[e]
__global__ __launch_bounds__(256) void cvv_kernel(const float* __restrict__ Wv,
                                                  const float* __restrict__ b2,
                                                  const float* __restrict__ bv,
                                                  float* __restrict__ cvv) {
    int e = blockIdx.x * 256 + threadIdx.x;
    float s = bv[e];
    #pragma unroll 8
    for (int d = 0; d < 512; ++d) s += b2[d] * Wv[(size_t)d * 512 + e];
    cvv[e] = s;
}

// ---------------- WW[2048][512] = W2[2048][512] @ Wv[512][512]  (fp32 tiled)
__global__ __launch_bounds__(256) void ww_kernel(const float* __restrict__ W2,
                                                 const float* __restrict__ Wv,
                                                 float* __restrict__ WW) {
    __shared__ float As[64][65];
    __shared__ float Bs[64][65];
    const int m0 = blockIdx.y * 64, n0 = blockIdx.x * 64;
    const int tid = threadIdx.x;
    const int tx = tid & 15, ty = tid >> 4;
    float acc[4][4] = {};
    for (int k0 = 0; k0 < 512; k0 += 64) {
        for (int i = tid; i < 4096; i += 256) {
            int r = i >> 6, c = i & 63;
            As[r][c] = W2[(size_t)(m0 + r) * 512 + k0 + c];
            Bs[r][c] = Wv[(size_t)(k0 + r) * 512 + n0 + c];
        }
        __syncthreads();
        for (int kk = 0; kk < 64; ++kk) {
            float a[4], b[4];
            #pragma unroll
            for (int i = 0; i < 4; ++i) a[i] = As[ty * 4 + i][kk];
            #pragma unroll
            for (int j = 0; j < 4; ++j) b[j] = Bs[kk][tx * 4 + j];
            #pragma unroll
            for (int i = 0; i < 4; ++i)
                #pragma unroll
                for (int j = 0; j < 4; ++j) acc[i][j] += a[i] * b[j];
        }
        __syncthreads();
    }
    #pragma unroll
    for (int i = 0; i < 4; ++i)
        #pragma unroll
        for (int j = 0; j < 4; ++j)
            WW[(size_t)(m0 + ty * 4 + i) * 512 + n0 + tx * 4 + j] = acc[i][j];
}

// ---------------- gather emb rows -> bf16 z
__global__ __launch_bounds__(256) void embed_kernel(const int* __restrict__ idx,
                                                    const float* __restrict__ emb,
                                                    u16* __restrict__ z) {
    int u = blockIdx.x * 256 + threadIdx.x;   // one unit = 8 elements
    int t = u >> 6;
    int d0 = (u & 63) * 8;
    int row = idx[t];
    const float4* src = (const float4*)(emb + (size_t)row * 512 + d0);
    float4 a = src[0], b = src[1];
    u16x8 o;
    o[0] = f2b(a.x); o[1] = f2b(a.y); o[2] = f2b(a.z); o[3] = f2b(a.w);
    o[4] = f2b(b.x); o[5] = f2b(b.y); o[6] = f2b(b.z); o[7] = f2b(b.w);
    *(u16x8*)(z + (size_t)t * 512 + d0) = o;
}

// ---------------- bf16 GEMM 128x128, BK=64, 4 waves (2x2), m97-style 2-barrier loop.
// R4: back to max co-residency — 32 KiB LDS -> ~5 blocks/CU (20 waves), letting
// cross-block wave overlap hide the barrier drain (beats intra-block pipelining
// for this short-K (nK=8), write-heavy GEMM; r1/r3 1-block/CU variants regressed).
// Fragment math / staging swizzle / accumulation order identical to all prior
// rounds -> bitwise-identical C1.
template <int RELU, int LNT>
__global__ __launch_bounds__(256) void gemm_bt128(const u16* __restrict__ A,
                                                  const u16* __restrict__ Bt,
                                                  const float* __restrict__ bias,
                                                  u16* __restrict__ C,
                                                  int N, int K) {
    __shared__ __align__(16) u16 As[128 * 64];   // 16 KB
    __shared__ __align__(16) u16 Bs[128 * 64];   // 16 KB
    const int tid = threadIdx.x;
    const int id = blockIdx.x;
    const int xcd = id & 7, sblk = id >> 3;
    const int n_idx = sblk & ((1 << LNT) - 1);
    const int m_idx = xcd + 8 * (sblk >> LNT);
    const int m0 = m_idx * 128, n0 = n_idx * 128;
    const int lane = tid & 63, quad = lane >> 4, l15 = lane & 15;
    const int wave = tid >> 6, wm = wave >> 1, wn = wave & 1;

    f32x4 acc[4][4] = {};

    const int nK = K >> 6;
    for (int kt = 0; kt < nK; ++kt) {
        __syncthreads();
        const int kb = kt * 64;
        #pragma unroll
        for (int r = 0; r < 4; ++r) {
            int u = tid + r * 256;
            int row = u >> 3;
            int cg = (u & 7) ^ (row & 7);
            const u16* ga = A + (size_t)(m0 + row) * K + kb + cg * 8;
            __builtin_amdgcn_global_load_lds((const __attribute__((address_space(1))) void*)ga,
                                             (__attribute__((address_space(3))) void*)(&As[u * 8]),
                                             16, 0, 0);
        }
        #pragma unroll
        for (int r = 0; r < 4; ++r) {
            int u = tid + r * 256;
            int row = u >> 3;
            int cg = (u & 7) ^ (row & 7);
            const u16* gb = Bt + (size_t)(n0 + row) * K + kb + cg * 8;
            __builtin_amdgcn_global_load_lds((const __attribute__((address_space(1))) void*)gb,
                                             (__attribute__((address_space(3))) void*)(&Bs[u * 8]),
                                             16, 0, 0);
        }
        __syncthreads();
        #pragma unroll
        for (int ks = 0; ks < 2; ++ks) {
            bf16x8_t af[4], bfr[4];
            #pragma unroll
            for (int mt = 0; mt < 4; ++mt) {
                int row = wm * 64 + mt * 16 + l15;
                int g = (ks * 4 + quad) ^ (row & 7);
                af[mt] = *(const bf16x8_t*)&As[row * 64 + g * 8];
            }
            #pragma unroll
            for (int nt = 0; nt < 4; ++nt) {
                int row = wn * 64 + nt * 16 + l15;
                int g = (ks * 4 + quad) ^ (row & 7);
                bfr[nt] = *(const bf16x8_t*)&Bs[row * 64 + g * 8];
            }
            #pragma unroll
            for (int mt = 0; mt < 4; ++mt)
                #pragma unroll
                for (int nt = 0; nt < 4; ++nt)
                    acc[mt][nt] = __builtin_amdgcn_mfma_f32_16x16x32_bf16(af[mt], bfr[nt],
                                                                          acc[mt][nt], 0, 0, 0);
        }
    }

    float bvv[4];
    #pragma unroll
    for (int nt = 0; nt < 4; ++nt) bvv[nt] = bias[n0 + wn * 64 + nt * 16 + l15];
    #pragma unroll
    for (int mt = 0; mt < 4; ++mt)
        #pragma unroll
        for (int nt = 0; nt < 4; ++nt)
            #pragma unroll
            for (int r = 0; r < 4; ++r) {
                int row = m0 + wm * 64 + mt * 16 + quad * 4 + r;
                int col = n0 + wn * 64 + nt * 16 + l15;
                float v = acc[mt][nt][r] + bvv[nt];
                if (RELU) v = fmaxf(v, 0.f);
                C[(size_t)row * N + col] = f2b(v);
            }
}

// ---------------- fused flash-style attention pool over 64-token chunks.
__global__ __launch_bounds__(256) void attn2_kernel(const u16* __restrict__ C1,
                                                    const u16* __restrict__ wv2t,
                                                    const float* __restrict__ ck2,
                                                    float* __restrict__ pbuf,
                                                    float* __restrict__ msbuf) {
    __shared__ __align__(16) u16 bsh[16 * 2048];   // 64 KB
    __shared__ float sc[64][8];                    // raw scores
    __shared__ float pp[64][8];                    // exp(s - m_c)
    __shared__ float mh[8];
    const int c = blockIdx.x, b = blockIdx.y, tid = threadIdx.x;
    const int w = tid >> 6, lane = tid & 63, quad = lane >> 4, l15 = lane & 15;

    for (int i = tid; i < 4096; i += 256)
        ((float4*)bsh)[i] = ((const float4*)wv2t)[i];
    __syncthreads();

    const int t0 = b * 1024 + c * 64;         // chunk token base
    // --- phase 1: wave w scores tokens t0 + w*16 .. +15
    {
        const u16* arow = C1 + (size_t)(t0 + w * 16 + l15) * 2048 + quad * 8;
        const u16* brow = &bsh[l15 * 2048 + quad * 8];
        f32x4 acc = {};
        #pragma unroll 4
        for (int kt = 0; kt < 64; ++kt) {
            bf16x8_t af = *(const bf16x8_t*)(arow + kt * 32);
            bf16x8_t bf = *(const bf16x8_t*)(brow + kt * 32);
            acc = __builtin_amdgcn_mfma_f32_16x16x32_bf16(af, bf, acc, 0, 0, 0);
        }
        if (l15 < 8) {
            float ck = ck2[l15];
            #pragma unroll
            for (int r = 0; r < 4; ++r)
                sc[w * 16 + quad * 4 + r][l15] = acc[r] + ck;
        }
    }
    __syncthreads();
    // --- chunk max per head
    if (tid < 8) {
        float m = -1e30f;
        for (int l = 0; l < 64; ++l) m = fmaxf(m, sc[l][tid]);
        mh[tid] = m;
    }
    __syncthreads();
    for (int i = tid; i < 512; i += 256) {
        int l = i >> 3, h = i & 7;
        pp[l][h] = __expf(sc[l][h] - mh[h]);
    }
    __syncthreads();
    if (tid < 8) {
        float s = 0.f;
        for (int l = 0; l < 64; ++l) s += pp[l][tid];
        float* mb = msbuf + ((size_t)b * NC_ + c) * 16;
        mb[tid] = mh[tid];
        mb[8 + tid] = s;
    }
    // --- phase 2: wave w owns cols [w*512, w*512+512); lane owns 8 cols
    const u16* crow = C1 + (size_t)t0 * 2048 + w * 512 + lane * 8;
    float acc2[8][8] = {};
    #pragma unroll 2
    for (int l = 0; l < 64; ++l) {
        u16x8 v = *(const u16x8*)(crow + (size_t)l * 2048);
        float av[8];
        #pragma unroll
        for (int hh = 0; hh < 8; ++hh) av[hh] = pp[l][hh];
        #pragma unroll
        for (int j = 0; j < 8; ++j) {
            float hf = b2f(v[j]);
            #pragma unroll
            for (int hh = 0; hh < 8; ++hh) acc2[hh][j] += av[hh] * hf;
        }
    }
    float* pw = pbuf + (((size_t)b * NC_ + c) * 8) * 2048 + w * 512 + lane * 8;
    #pragma unroll
    for (int hh = 0; hh < 8; ++hh) {
        float4 lo, hi;
        lo.x = acc2[hh][0]; lo.y = acc2[hh][1]; lo.z = acc2[hh][2]; lo.w = acc2[hh][3];
        hi.x = acc2[hh][4]; hi.y = acc2[hh][5]; hi.z = acc2[hh][6]; hi.w = acc2[hh][7];
        *(float4*)(pw + (size_t)hh * 2048) = lo;
        *(float4*)(pw + (size_t)hh * 2048 + 4) = hi;
    }
}

// ---------------- ctx partials with flash fold:
__global__ __launch_bounds__(256) void ctx_kernel(const float* __restrict__ pbuf,
                                                  const float* __restrict__ msbuf,
                                                  const float* __restrict__ WW,
                                                  float* __restrict__ ctxp) {
    __shared__ float g1c[8 * 512];
    __shared__ float scl[NC_ * 8];
    const int kc = blockIdx.x, b = blockIdx.y, tid = threadIdx.x;
    if (tid < 8) {
        const float* mb = msbuf + (size_t)b * NC_ * 16;
        float m = -1e30f;
        for (int c = 0; c < NC_; ++c) m = fmaxf(m, mb[c * 16 + tid]);
        float den = 0.f;
        for (int c = 0; c < NC_; ++c) den += mb[c * 16 + 8 + tid] * __expf(mb[c * 16 + tid] - m);
        float inv = 1.f / den;
        for (int c = 0; c < NC_; ++c) scl[c * 8 + tid] = __expf(mb[c * 16 + tid] - m) * inv;
    }
    __syncthreads();
    for (int i = tid; i < 4096; i += 256) {
        int hh = i >> 9, k = i & 511;
        float s = 0.f;
        #pragma unroll
        for (int c = 0; c < NC_; ++c)
            s += pbuf[(((size_t)b * NC_ + c) * 8 + hh) * 2048 + kc * 512 + k] * scl[c * 8 + hh];
        g1c[hh * 512 + k] = s;
    }
    __syncthreads();
    const int e1 = tid, e2 = tid + 256;
    const int h1 = e1 >> 6, h2 = e2 >> 6;
    float a1 = 0.f, a2 = 0.f;
    #pragma unroll 2
    for (int k = 0; k < 512; k += 4) {
        float4 g1v = *(const float4*)&g1c[h1 * 512 + k];
        float4 g2v = *(const float4*)&g1c[h2 * 512 + k];
        const float* wr = WW + (size_t)(kc * 512 + k) * 512;
        a1 += g1v.x * wr[e1] + g1v.y * wr[512 + e1] + g1v.z * wr[1024 + e1] + g1v.w * wr[1536 + e1];
        a2 += g2v.x * wr[e2] + g2v.y * wr[512 + e2] + g2v.z * wr[1024 + e2] + g2v.w * wr[1536 + e2];
    }
    ctxp[((size_t)b * 4 + kc) * 512 + e1] = a1;
    ctxp[((size_t)b * 4 + kc) * 512 + e2] = a2;
}

// ---------------- per-set: ctx fold + pooled = ctx@Wo + bo; LN -> y
__global__ __launch_bounds__(256) void pool2_kernel(const float* __restrict__ ctxp,
                                                    const float* __restrict__ cvv,
                                                    const float* __restrict__ Wo,
                                                    const float* __restrict__ bo,
                                                    const float* __restrict__ g,
                                                    const float* __restrict__ lb,
                                                    float* __restrict__ y) {
    __shared__ float ctx[512];
    __shared__ float red[8];
    __shared__ float stats[2];
    const int b = blockIdx.x, tid = threadIdx.x;
    for (int i = tid; i < 512; i += 256) {
        float s = cvv[i];
        #pragma unroll
        for (int kc = 0; kc < 4; ++kc) s += ctxp[((size_t)b * 4 + kc) * 512 + i];
        ctx[i] = s;
    }
    __syncthreads();
    float pv[2]; float psum = 0.f, psq = 0.f;
    #pragma unroll
    for (int ph = 0; ph < 2; ++ph) {
        int e2 = tid + ph * 256;
        float acc = bo[e2];
        #pragma unroll 8
        for (int ee = 0; ee < 512; ++ee) acc += ctx[ee] * Wo[(size_t)ee * 512 + e2];
        pv[ph] = acc; psum += acc; psq += acc * acc;
    }
    for (int off = 32; off; off >>= 1) { psum += __shfl_xor(psum, off, 64); psq += __shfl_xor(psq, off, 64); }
    const int w = tid >> 6, lane = tid & 63;
    if (lane == 0) { red[w] = psum; red[4 + w] = psq; }
    __syncthreads();
    if (tid == 0) {
        float s = red[0] + red[1] + red[2] + red[3];
        float q2 = red[4] + red[5] + red[6] + red[7];
        float mu = s / 512.f;
        float var = q2 / 512.f - mu * mu;
        stats[0] = mu; stats[1] = 1.f / sqrtf(var + 1e-5f);
    }
    __syncthreads();
    #pragma unroll
    for (int ph = 0; ph < 2; ++ph) {
        int e2 = tid + ph * 256;
        y[(size_t)b * 512 + e2] = (pv[ph] - stats[0]) * stats[1] * g[e2] + lb[e2];
    }
}

// ---------------- head MLP layer 1: hid = relu(y@Wh1 + bh1)
__global__ __launch_bounds__(256) void h1_kernel(const float* __restrict__ y,
                                                 const float* __restrict__ Wh1,
                                                 const float* __restrict__ bh1,
                                                 float* __restrict__ hid) {
    __shared__ float ys[512];
    const int b = blockIdx.y, tid = threadIdx.x;
    ys[tid] = y[(size_t)b * 512 + tid];
    ys[tid + 256] = y[(size_t)b * 512 + tid + 256];
    __syncthreads();
    int j = blockIdx.x * 256 + tid;
    float acc = bh1[j];
    #pragma unroll 8
    for (int dd = 0; dd < 512; ++dd) acc += ys[dd] * Wh1[(size_t)dd * 2048 + j];
    hid[(size_t)b * 2048 + j] = fmaxf(acc, 0.f);
}

// ---------------- head MLP layer 2: logits = hid@Wh2 + bh2
__global__ __launch_bounds__(256) void h2_kernel(const float* __restrict__ hid,
                                                 const float* __restrict__ Wh2,
                                                 const float* __restrict__ bh2,
                                                 float* __restrict__ out) {
    __shared__ float red[4];
    const int b = blockIdx.x, tid = threadIdx.x;
    float s = 0.f;
    #pragma unroll
    for (int j = tid; j < 2048; j += 256) s += hid[(size_t)b * 2048 + j] * Wh2[j];
    for (int off = 32; off; off >>= 1) s += __shfl_xor(s, off, 64);
    const int w = tid >> 6, lane = tid & 63;
    if (lane == 0) red[w] = s;
    __syncthreads();
    if (tid == 0) out[b] = red[0] + red[1] + red[2] + red[3] + bh2[0];
}

extern "C" void kernel_launch(void* const* d_in, const int* in_sizes, int n_in,
                              void* d_out, int out_size, void* d_ws, size_t ws_size,
                              hipStream_t stream) {
    const int*   mut_idx = (const int*)d_in[0];
    const float* emb  = (const float*)d_in[2];
    const float* W1   = (const float*)d_in[3];
    const float* b1   = (const float*)d_in[4];
    const float* W2   = (const float*)d_in[5];
    const float* b2   = (const float*)d_in[6];
    const float* q    = (const float*)d_in[7];
    const float* Wq   = (const float*)d_in[8];
    const float* bq   = (const float*)d_in[9];
    const float* Wk   = (const float*)d_in[10];
    const float* bk   = (const float*)d_in[11];
    const float* Wv   = (const float*)d_in[12];
    const float* bv   = (const float*)d_in[13];
    const float* Wo   = (const float*)d_in[14];
    const float* bo   = (const float*)d_in[15];
    const float* ln_g = (const float*)d_in[16];
    const float* ln_b = (const float*)d_in[17];
    const float* Wh1  = (const float*)d_in[18];
    const float* bh1  = (const float*)d_in[19];
    const float* Wh2  = (const float*)d_in[20];
    const float* bh2  = (const float*)d_in[21];
    float* out = (float*)d_out;

    // workspace layout (256B aligned)
    char* p = (char*)d_ws;
    auto alloc = [&](size_t bytes) {
        char* r = p; p += (bytes + 255) & ~(size_t)255; return r;
    };
    u16*  W1t  = (u16*)alloc((size_t)H_ * D_ * 2);              // 2 MB
    u16*  wv2t = (u16*)alloc((size_t)16 * H_ * 2);              // 64 KB
    float* WW  = (float*)alloc((size_t)H_ * D_ * 4);            // 4 MB
    float* qp  = (float*)alloc(D_ * 4);
    float* wke = (float*)alloc((size_t)D_ * NH_ * 4);
    float* cke = (float*)alloc(NH_ * 4);
    float* ck2 = (float*)alloc(NH_ * 4);
    float* cvv = (float*)alloc(D_ * 4);
    float* pbuf = (float*)alloc((size_t)B_ * NC_ * NH_ * H_ * 4); // 67 MB
    float* msbuf = (float*)alloc((size_t)B_ * NC_ * 16 * 4);    // 64 KB
    float* ctxp = (float*)alloc((size_t)B_ * 4 * D_ * 4);       // 512 KB
    float* ybuf = (float*)alloc((size_t)B_ * D_ * 4);
    float* hid  = (float*)alloc((size_t)B_ * H_ * 4);
    u16*  z    = (u16*)alloc((size_t)TOT * D_ * 2);             // 67 MB
    u16*  C1   = (u16*)alloc((size_t)TOT * H_ * 2);             // 268 MB

    // setup / weight folding
    transpose_cvt<<<dim3(H_ / 32, D_ / 32), dim3(32, 8), 0, stream>>>(W1, W1t, D_, H_);
    qp_kernel<<<2, 256, 0, stream>>>(q, Wq, bq, qp);
    wke_kernel<<<16, 256, 0, stream>>>(Wk, bk, qp, wke, cke);
    wv2_kernel<<<64, 256, 0, stream>>>(W2, wke, cke, b2, wv2t, ck2);
    cvv_kernel<<<2, 256, 0, stream>>>(Wv, b2, bv, cvv);
    ww_kernel<<<dim3(8, 32), 256, 0, stream>>>(W2, Wv, WW);

    // phi layer-1 only (layer-2 algebraically folded away)
    embed_kernel<<<TOT / 4, 256, 0, stream>>>(mut_idx, emb, z);
    gemm_bt128<1, 4><<<dim3((TOT / 128) * (H_ / 128)), 256, 0, stream>>>(z, W1t, b1, C1, H_, D_);

    // fused flash-style attention pool on C1 + folded tail
    attn2_kernel<<<dim3(NC_, B_), 256, 0, stream>>>(C1, wv2t, ck2, pbuf, msbuf);
    ctx_kernel<<<dim3(4, B_), 256, 0, stream>>>(pbuf, msbuf, WW, ctxp);
    pool2_kernel<<<B_, 256, 0, stream>>>(ctxp, cvv, Wo, bo, ln_g, ln_b, ybuf);
    h1_kernel<<<dim3(H_ / 256, B_), 256, 0, stream>>>(ybuf, Wh1, bh1, hid);
    h2_kernel<<<B_, 256, 0, stream>>>(hid, Wh2, bh2, out);
}

// Round 5
// 826.238 us; speedup vs baseline: 1.1593x; 1.1593x over previous
//
#include <hip/hip_runtime.h>
#include <hip/hip_bf16.h>

using u16 = unsigned short;
typedef __bf16 bf16x8_t __attribute__((ext_vector_type(8)));
typedef float    f32x4  __attribute__((ext_vector_type(4)));
typedef unsigned short u16x8 __attribute__((ext_vector_type(8)));

#define B_  64
#define L_  1024
#define TOT 65536
#define D_  512
#define H_  2048
#define NH_ 8

__device__ __forceinline__ float b2f(u16 x) {
    union { unsigned int i; float f; } v; v.i = ((unsigned int)x) << 16; return v.f;
}
__device__ __forceinline__ u16 f2b(float f) {
    union { float f; unsigned int i; } v; v.f = f;
    unsigned int i = v.i;
    unsigned int r = i + 0x7FFFu + ((i >> 16) & 1u);   // RNE
    return (u16)(r >> 16);
}

// ---------------- transpose + fp32->bf16 convert:  in[R][C] f32 -> out[C][R] bf16
__global__ __launch_bounds__(256) void transpose_cvt(const float* __restrict__ in,
                                                     u16* __restrict__ out, int R, int C) {
    __shared__ float tile[32][33];
    int c0 = blockIdx.x * 32, r0 = blockIdx.y * 32;
    int tx = threadIdx.x, ty = threadIdx.y;
    #pragma unroll
    for (int i = 0; i < 4; ++i)
        tile[ty + 8 * i][tx] = in[(size_t)(r0 + ty + 8 * i) * C + c0 + tx];
    __syncthreads();
    #pragma unroll
    for (int i = 0; i < 4; ++i)
        out[(size_t)(c0 + ty + 8 * i) * R + r0 + tx] = f2b(tile[tx][ty + 8 * i]);
}

// ---------------- qp = q @ Wq + bq
__global__ __launch_bounds__(256) void qp_kernel(const float* __restrict__ q,
                                                 const float* __restrict__ Wq,
                                                 const float* __restrict__ bq,
                                                 float* __restrict__ qp) {
    __shared__ float qs[512];
    int tid = threadIdx.x;
    qs[tid] = q[tid]; qs[tid + 256] = q[tid + 256];
    __syncthreads();
    int j = blockIdx.x * 256 + tid;
    float acc = bq[j];
    for (int d = 0; d < 512; ++d) acc += qs[d] * Wq[(size_t)d * 512 + j];
    qp[j] = acc;
}

// ---------------- wke[d][h] = 0.125*sum_j Wk[d,h*64+j]*qp[h*64+j];  cke[h] from bk
__global__ __launch_bounds__(256) void wke_kernel(const float* __restrict__ Wk,
                                                  const float* __restrict__ bk,
                                                  const float* __restrict__ qp,
                                                  float* __restrict__ wke,
                                                  float* __restrict__ cke) {
    __shared__ float qs[512];
    int tid = threadIdx.x;
    qs[tid] = qp[tid]; qs[tid + 256] = qp[tid + 256];
    __syncthreads();
    int d = blockIdx.x * 32 + (tid >> 3);
    int h = tid & 7;
    float s = 0.f;
    for (int j = 0; j < 64; ++j) s += Wk[(size_t)d * 512 + h * 64 + j] * qs[h * 64 + j];
    wke[d * 8 + h] = 0.125f * s;
    if (blockIdx.x == 0 && tid < 8) {
        float c = 0.f;
        for (int j = 0; j < 64; ++j) c += bk[tid * 64 + j] * qs[tid * 64 + j];
        cke[tid] = 0.125f * c;
    }
}

// ---------------- wv2t[h][k] = bf16( sum_d W2[k][d]*wke[d][h] ), rows 8..15 zero.
// ck2[h] = sum_d b2[d]*wke[d][h] + cke[h]
__global__ __launch_bounds__(256) void wv2_kernel(const float* __restrict__ W2,
                                                  const float* __restrict__ wke,
                                                  const float* __restrict__ cke,
                                                  const float* __restrict__ b2,
                                                  u16* __restrict__ wv2t,
                                                  float* __restrict__ ck2) {
    __shared__ float wk[512 * 8];
    int tid = threadIdx.x;
    for (int i = tid; i < 4096; i += 256) wk[i] = wke[i];
    __syncthreads();
    int k = blockIdx.x * 32 + (tid >> 3);
    int h = tid & 7;
    float s = 0.f;
    const float* row = W2 + (size_t)k * 512;
    for (int d = 0; d < 512; ++d) s += row[d] * wk[d * 8 + h];
    wv2t[(size_t)h * 2048 + k] = f2b(s);
    wv2t[(size_t)(h + 8) * 2048 + k] = 0;
    if (blockIdx.x == 0 && tid < 8) {
        float c = 0.f;
        for (int d = 0; d < 512; ++d) c += b2[d] * wk[d * 8 + tid];
        ck2[tid] = c + cke[tid];
    }
}

// ---------------- cvv[e] = sum_d b2[d]*Wv[d][e] + bv[e]
__global__ __launch_bounds__(256) void cvv_kernel(const float* __restrict__ Wv,
                                                  const float* __restrict__ b2,
                                                  const float* __restrict__ bv,
                                                  float* __restrict__ cvv) {
    int e = blockIdx.x * 256 + threadIdx.x;
    float s = bv[e];
    for (int d = 0; d < 512; ++d) s += b2[d] * Wv[(size_t)d * 512 + e];
    cvv[e] = s;
}

// ---------------- WW[2048][512] = W2[2048][512] @ Wv[512][512]  (fp32 tiled)
__global__ __launch_bounds__(256) void ww_kernel(const float* __restrict__ W2,
                                                 const float* __restrict__ Wv,
                                                 float* __restrict__ WW) {
    __shared__ float As[64][65];
    __shared__ float Bs[64][65];
    const int m0 = blockIdx.y * 64, n0 = blockIdx.x * 64;
    const int tid = threadIdx.x;
    const int tx = tid & 15, ty = tid >> 4;
    float acc[4][4] = {};
    for (int k0 = 0; k0 < 512; k0 += 64) {
        for (int i = tid; i < 4096; i += 256) {
            int r = i >> 6, c = i & 63;
            As[r][c] = W2[(size_t)(m0 + r) * 512 + k0 + c];
            Bs[r][c] = Wv[(size_t)(k0 + r) * 512 + n0 + c];
        }
        __syncthreads();
        for (int kk = 0; kk < 64; ++kk) {
            float a[4], b[4];
            #pragma unroll
            for (int i = 0; i < 4; ++i) a[i] = As[ty * 4 + i][kk];
            #pragma unroll
            for (int j = 0; j < 4; ++j) b[j] = Bs[kk][tx * 4 + j];
            #pragma unroll
            for (int i = 0; i < 4; ++i)
                #pragma unroll
                for (int j = 0; j < 4; ++j) acc[i][j] += a[i] * b[j];
        }
        __syncthreads();
    }
    #pragma unroll
    for (int i = 0; i < 4; ++i)
        #pragma unroll
        for (int j = 0; j < 4; ++j)
            WW[(size_t)(m0 + ty * 4 + i) * 512 + n0 + tx * 4 + j] = acc[i][j];
}

// ---------------- gather emb rows -> bf16 z
__global__ __launch_bounds__(256) void embed_kernel(const int* __restrict__ idx,
                                                    const float* __restrict__ emb,
                                                    u16* __restrict__ z) {
    int u = blockIdx.x * 256 + threadIdx.x;   // one unit = 8 elements
    int t = u >> 6;
    int d0 = (u & 63) * 8;
    int row = idx[t];
    const float4* src = (const float4*)(emb + (size_t)row * 512 + d0);
    float4 a = src[0], b = src[1];
    u16x8 o;
    o[0] = f2b(a.x); o[1] = f2b(a.y); o[2] = f2b(a.z); o[3] = f2b(a.w);
    o[4] = f2b(b.x); o[5] = f2b(b.y); o[6] = f2b(b.z); o[7] = f2b(b.w);
    *(u16x8*)(z + (size_t)t * 512 + d0) = o;
}

// ---------------- bf16 GEMM 256x128, BK=64, 8 waves (round-0 structure, best measured)
// + FUSED SCORE EPILOGUE: restage the relu'd bf16 C-tile into As (same swizzle),
// stage the wv2t 128-col slice into Bs, 8 MFMAs -> score partials
// spb[n_idx][token][h] (fp32). Same bf16 values as the old attn2 phase-1 read;
// only the fp32 association changes (per-128-k partials, summed in fixed n order).
template <int RELU, int LNT>
__global__ __launch_bounds__(512) void gemm_bt256(const u16* __restrict__ A,
                                                  const u16* __restrict__ Bt,
                                                  const float* __restrict__ bias,
                                                  u16* __restrict__ C,
                                                  const u16* __restrict__ wv2t,
                                                  float* __restrict__ spb,
                                                  int N, int K) {
    __shared__ __align__(16) u16 As[256 * 64];
    __shared__ __align__(16) u16 Bs[128 * 64];
    const int tid = threadIdx.x;
    const int id = blockIdx.x;
    const int xcd = id & 7, s = id >> 3;
    const int n_idx = s & ((1 << LNT) - 1);
    const int m_idx = xcd + 8 * (s >> LNT);
    const int m0 = m_idx * 256, n0 = n_idx * 128;
    const int lane = tid & 63, quad = lane >> 4, l15 = lane & 15;
    const int wave = tid >> 6, wm = wave >> 1, wn = wave & 1;

    f32x4 acc[4][4] = {};

    const int nK = K >> 6;
    for (int kt = 0; kt < nK; ++kt) {
        __syncthreads();
        const int kb = kt * 64;
        #pragma unroll
        for (int r = 0; r < 4; ++r) {
            int u = tid + r * 512;
            int row = u >> 3;
            int cg = (u & 7) ^ (row & 7);
            const u16* ga = A + (size_t)(m0 + row) * K + kb + cg * 8;
            __builtin_amdgcn_global_load_lds((const __attribute__((address_space(1))) void*)ga,
                                             (__attribute__((address_space(3))) void*)(&As[u * 8]),
                                             16, 0, 0);
        }
        #pragma unroll
        for (int r = 0; r < 2; ++r) {
            int u = tid + r * 512;
            int row = u >> 3;
            int cg = (u & 7) ^ (row & 7);
            const u16* gb = Bt + (size_t)(n0 + row) * K + kb + cg * 8;
            __builtin_amdgcn_global_load_lds((const __attribute__((address_space(1))) void*)gb,
                                             (__attribute__((address_space(3))) void*)(&Bs[u * 8]),
                                             16, 0, 0);
        }
        __syncthreads();
        #pragma unroll
        for (int ks = 0; ks < 2; ++ks) {
            bf16x8_t af[4], bfr[4];
            #pragma unroll
            for (int mt = 0; mt < 4; ++mt) {
                int row = wm * 64 + mt * 16 + l15;
                int g = (ks * 4 + quad) ^ (row & 7);
                af[mt] = *(const bf16x8_t*)&As[row * 64 + g * 8];
            }
            #pragma unroll
            for (int nt = 0; nt < 4; ++nt) {
                int row = wn * 64 + nt * 16 + l15;
                int g = (ks * 4 + quad) ^ (row & 7);
                bfr[nt] = *(const bf16x8_t*)&Bs[row * 64 + g * 8];
            }
            #pragma unroll
            for (int mt = 0; mt < 4; ++mt)
                #pragma unroll
                for (int nt = 0; nt < 4; ++nt)
                    acc[mt][nt] = __builtin_amdgcn_mfma_f32_16x16x32_bf16(af[mt], bfr[nt],
                                                                          acc[mt][nt], 0, 0, 0);
        }
    }

    float bvv[4];
    #pragma unroll
    for (int nt = 0; nt < 4; ++nt) bvv[nt] = bias[n0 + wn * 64 + nt * 16 + l15];
    #pragma unroll
    for (int mt = 0; mt < 4; ++mt)
        #pragma unroll
        for (int nt = 0; nt < 4; ++nt)
            #pragma unroll
            for (int r = 0; r < 4; ++r) {
                int row = m0 + wm * 64 + mt * 16 + quad * 4 + r;
                int col = n0 + wn * 64 + nt * 16 + l15;
                float v = acc[mt][nt][r] + bvv[nt];
                if (RELU) v = fmaxf(v, 0.f);
                C[(size_t)row * N + col] = f2b(v);
            }

    // ---- fused score partials: spb[n_idx][token][h] = C_tile @ wv2t_slice^T
    __syncthreads();     // all main-loop LDS reads finished in every wave
    f32x4 accs[2] = {};
    #pragma unroll
    for (int p = 0; p < 2; ++p) {
        if (wn == p) {   // this half's columns live in these 4 waves
            #pragma unroll
            for (int mt = 0; mt < 4; ++mt)
                #pragma unroll
                for (int nt = 0; nt < 4; ++nt)
                    #pragma unroll
                    for (int r = 0; r < 4; ++r) {
                        int row = wm * 64 + mt * 16 + quad * 4 + r;
                        int c   = nt * 16 + l15;
                        float v = fmaxf(acc[mt][nt][r] + bvv[nt], 0.f);
                        As[row * 64 + (((c >> 3) ^ (row & 7)) << 3) + (c & 7)] = f2b(v);
                    }
        }
        if (tid < 128) { // wv2t slice: 16 rows x 64 cols, same swizzle
            int hrow = tid >> 3, cg = tid & 7;
            u16x8 v = *(const u16x8*)&wv2t[(size_t)hrow * 2048 + n0 + p * 64 + cg * 8];
            *(u16x8*)&Bs[hrow * 64 + ((cg ^ (hrow & 7)) << 3)] = v;
        }
        __syncthreads();
        #pragma unroll
        for (int m2 = 0; m2 < 2; ++m2) {
            int arow = (wave * 2 + m2) * 16 + l15;
            #pragma unroll
            for (int ks = 0; ks < 2; ++ks) {
                bf16x8_t av = *(const bf16x8_t*)&As[arow * 64 + (((ks * 4 + quad) ^ (arow & 7)) << 3)];
                bf16x8_t bv = *(const bf16x8_t*)&Bs[l15 * 64 + (((ks * 4 + quad) ^ (l15 & 7)) << 3)];
                accs[m2] = __builtin_amdgcn_mfma_f32_16x16x32_bf16(av, bv, accs[m2], 0, 0, 0);
            }
        }
        __syncthreads();
    }
    if (l15 < 8) {
        #pragma unroll
        for (int m2 = 0; m2 < 2; ++m2)
            #pragma unroll
            for (int r = 0; r < 4; ++r) {
                int row = m0 + (wave * 2 + m2) * 16 + quad * 4 + r;
                spb[((size_t)n_idx * TOT + row) * 8 + l15] = accs[m2][r];
            }
    }
}

// ---------------- softmax over full set: s = sum_n spb + ck2; p = softmax_l(s)
__global__ __launch_bounds__(256) void softmax_kernel(const float* __restrict__ spb,
                                                      const float* __restrict__ ck2,
                                                      float* __restrict__ pfin) {
    __shared__ float ps[1024 * 8];   // 32 KB
    __shared__ float red[32 * 8];
    __shared__ float mh[8], dn[8];
    const int b = blockIdx.x, tid = threadIdx.x;
    for (int i = tid; i < 8192; i += 256) {
        int l = i >> 3, h = i & 7;
        size_t t = (size_t)b * 1024 + l;
        float s = ck2[h];
        #pragma unroll
        for (int n = 0; n < 16; ++n) s += spb[((size_t)n * TOT + t) * 8 + h];
        ps[l * 8 + h] = s;
    }
    __syncthreads();
    {
        int slot = tid >> 3, h = tid & 7;
        float m = -1e30f;
        for (int i = 0; i < 32; ++i) m = fmaxf(m, ps[(slot + 32 * i) * 8 + h]);
        red[slot * 8 + h] = m;
    }
    __syncthreads();
    if (tid < 8) {
        float m = -1e30f;
        for (int s2 = 0; s2 < 32; ++s2) m = fmaxf(m, red[s2 * 8 + tid]);
        mh[tid] = m;
    }
    __syncthreads();
    for (int i = tid; i < 8192; i += 256) {
        int l = i >> 3, h = i & 7;
        ps[l * 8 + h] = __expf(ps[l * 8 + h] - mh[h]);
    }
    __syncthreads();
    {
        int slot = tid >> 3, h = tid & 7;
        float sum = 0.f;
        for (int i = 0; i < 32; ++i) sum += ps[(slot + 32 * i) * 8 + h];
        red[slot * 8 + h] = sum;
    }
    __syncthreads();
    if (tid < 8) {
        float sum = 0.f;
        for (int s2 = 0; s2 < 32; ++s2) sum += red[s2 * 8 + tid];
        dn[tid] = 1.f / sum;
    }
    __syncthreads();
    for (int i = tid; i < 8192; i += 256) {
        int l = i >> 3, h = i & 7;
        pfin[((size_t)b * 1024 + l) * 8 + h] = ps[l * 8 + h] * dn[h];
    }
}

// ---------------- pv: g1[b][h][k] = sum_l p[l][h] * C1[b*1024+l][k]  (one C1 pass)
__global__ __launch_bounds__(256) void pv_kernel(const u16* __restrict__ C1,
                                                 const float* __restrict__ pfin,
                                                 float* __restrict__ g1) {
    __shared__ float psl[1024 * 8];       // 32 KB
    __shared__ float red[4 * 8 * 128];    // 16 KB
    const int kc = blockIdx.x, b = blockIdx.y, tid = threadIdx.x;
    const int lane = tid & 63, wave = tid >> 6;
    const int colgrp = tid & 15, slot = tid >> 4;   // 16 col-groups x 16 l-slots
    for (int i = tid; i < 8192; i += 256)
        psl[i] = pfin[(size_t)b * 8192 + i];
    __syncthreads();
    const u16* base = C1 + (size_t)(b * 1024 + slot) * 2048 + kc * 128 + colgrp * 8;
    float a[8][8] = {};   // [h][j]
    for (int i = 0; i < 64; ++i) {        // l = slot + 16*i
        int l = slot + 16 * i;
        u16x8 v = *(const u16x8*)(base + (size_t)16 * i * 2048);
        float4 p0 = *(const float4*)&psl[l * 8];
        float4 p1 = *(const float4*)&psl[l * 8 + 4];
        float pv8[8] = {p0.x, p0.y, p0.z, p0.w, p1.x, p1.y, p1.z, p1.w};
        #pragma unroll
        for (int j = 0; j < 8; ++j) {
            float hf = b2f(v[j]);
            #pragma unroll
            for (int h = 0; h < 8; ++h) a[h][j] += pv8[h] * hf;
        }
    }
    // reduce the 4 in-wave slots (lane bits 4-5), then 4 waves via LDS
    #pragma unroll
    for (int h = 0; h < 8; ++h)
        #pragma unroll
        for (int j = 0; j < 8; ++j) {
            a[h][j] += __shfl_xor(a[h][j], 16, 64);
            a[h][j] += __shfl_xor(a[h][j], 32, 64);
        }
    if (lane < 16) {
        #pragma unroll
        for (int h = 0; h < 8; ++h)
            #pragma unroll
            for (int j = 0; j < 8; ++j)
                red[(wave * 8 + h) * 128 + lane * 8 + j] = a[h][j];
    }
    __syncthreads();
    for (int i = tid; i < 1024; i += 256) {
        int h = i >> 7, cj = i & 127;
        float sv = red[(0 * 8 + h) * 128 + cj] + red[(1 * 8 + h) * 128 + cj]
                 + red[(2 * 8 + h) * 128 + cj] + red[(3 * 8 + h) * 128 + cj];
        g1[((size_t)b * 8 + h) * 2048 + kc * 128 + cj] = sv;
    }
}

// ---------------- ctx partials: ctxp = g1 @ WW (kc slice); out h = e>>6 (folded algebra)
__global__ __launch_bounds__(256) void ctx_kernel(const float* __restrict__ g1,
                                                  const float* __restrict__ WW,
                                                  float* __restrict__ ctxp) {
    __shared__ float g1c[8 * 512];
    const int kc = blockIdx.x, b = blockIdx.y, tid = threadIdx.x;
    for (int i = tid; i < 4096; i += 256) {
        int hh = i >> 9, k = i & 511;
        g1c[hh * 512 + k] = g1[((size_t)b * 8 + hh) * 2048 + kc * 512 + k];
    }
    __syncthreads();
    const int e1 = tid, e2 = tid + 256;
    const int h1 = e1 >> 6, h2 = e2 >> 6;
    float a1 = 0.f, a2 = 0.f;
    for (int k = 0; k < 512; k += 4) {
        float4 g1v = *(const float4*)&g1c[h1 * 512 + k];
        float4 g2v = *(const float4*)&g1c[h2 * 512 + k];
        const float* wr = WW + (size_t)(kc * 512 + k) * 512;
        a1 += g1v.x * wr[e1] + g1v.y * wr[512 + e1] + g1v.z * wr[1024 + e1] + g1v.w * wr[1536 + e1];
        a2 += g2v.x * wr[e2] + g2v.y * wr[512 + e2] + g2v.z * wr[1024 + e2] + g2v.w * wr[1536 + e2];
    }
    ctxp[((size_t)b * 4 + kc) * 512 + e1] = a1;
    ctxp[((size_t)b * 4 + kc) * 512 + e2] = a2;
}

// ---------------- per-set: ctx fold + pooled = ctx@Wo + bo; LN -> y
__global__ __launch_bounds__(256) void pool2_kernel(const float* __restrict__ ctxp,
                                                    const float* __restrict__ cvv,
                                                    const float* __restrict__ Wo,
                                                    const float* __restrict__ bo,
                                                    const float* __restrict__ g,
                                                    const float* __restrict__ lb,
                                                    float* __restrict__ y) {
    __shared__ float ctx[512];
    __shared__ float red[8];
    __shared__ float stats[2];
    const int b = blockIdx.x, tid = threadIdx.x;
    for (int i = tid; i < 512; i += 256) {
        float s = cvv[i];
        #pragma unroll
        for (int kc = 0; kc < 4; ++kc) s += ctxp[((size_t)b * 4 + kc) * 512 + i];
        ctx[i] = s;
    }
    __syncthreads();
    float pv[2]; float psum = 0.f, psq = 0.f;
    #pragma unroll
    for (int ph = 0; ph < 2; ++ph) {
        int e2 = tid + ph * 256;
        float acc = bo[e2];
        for (int ee = 0; ee < 512; ++ee) acc += ctx[ee] * Wo[(size_t)ee * 512 + e2];
        pv[ph] = acc; psum += acc; psq += acc * acc;
    }
    for (int off = 32; off; off >>= 1) { psum += __shfl_xor(psum, off, 64); psq += __shfl_xor(psq, off, 64); }
    const int w = tid >> 6, lane = tid & 63;
    if (lane == 0) { red[w] = psum; red[4 + w] = psq; }
    __syncthreads();
    if (tid == 0) {
        float s = red[0] + red[1] + red[2] + red[3];
        float q2 = red[4] + red[5] + red[6] + red[7];
        float mu = s / 512.f;
        float var = q2 / 512.f - mu * mu;
        stats[0] = mu; stats[1] = 1.f / sqrtf(var + 1e-5f);
    }
    __syncthreads();
    #pragma unroll
    for (int ph = 0; ph < 2; ++ph) {
        int e2 = tid + ph * 256;
        y[(size_t)b * 512 + e2] = (pv[ph] - stats[0]) * stats[1] * g[e2] + lb[e2];
    }
}

// ---------------- head MLP layer 1: hid = relu(y@Wh1 + bh1)
__global__ __launch_bounds__(256) void h1_kernel(const float* __restrict__ y,
                                                 const float* __restrict__ Wh1,
                                                 const float* __restrict__ bh1,
                                                 float* __restrict__ hid) {
    __shared__ float ys[512];
    const int b = blockIdx.y, tid = threadIdx.x;
    ys[tid] = y[(size_t)b * 512 + tid];
    ys[tid + 256] = y[(size_t)b * 512 + tid + 256];
    __syncthreads();
    int j = blockIdx.x * 256 + tid;
    float acc = bh1[j];
    for (int dd = 0; dd < 512; ++dd) acc += ys[dd] * Wh1[(size_t)dd * 2048 + j];
    hid[(size_t)b * 2048 + j] = fmaxf(acc, 0.f);
}

// ---------------- head MLP layer 2: logits = hid@Wh2 + bh2
__global__ __launch_bounds__(256) void h2_kernel(const float* __restrict__ hid,
                                                 const float* __restrict__ Wh2,
                                                 const float* __restrict__ bh2,
                                                 float* __restrict__ out) {
    __shared__ float red[4];
    const int b = blockIdx.x, tid = threadIdx.x;
    float s = 0.f;
    for (int j = tid; j < 2048; j += 256) s += hid[(size_t)b * 2048 + j] * Wh2[j];
    for (int off = 32; off; off >>= 1) s += __shfl_xor(s, off, 64);
    const int w = tid >> 6, lane = tid & 63;
    if (lane == 0) red[w] = s;
    __syncthreads();
    if (tid == 0) out[b] = red[0] + red[1] + red[2] + red[3] + bh2[0];
}

extern "C" void kernel_launch(void* const* d_in, const int* in_sizes, int n_in,
                              void* d_out, int out_size, void* d_ws, size_t ws_size,
                              hipStream_t stream) {
    const int*   mut_idx = (const int*)d_in[0];
    const float* emb  = (const float*)d_in[2];
    const float* W1   = (const float*)d_in[3];
    const float* b1   = (const float*)d_in[4];
    const float* W2   = (const float*)d_in[5];
    const float* b2   = (const float*)d_in[6];
    const float* q    = (const float*)d_in[7];
    const float* Wq   = (const float*)d_in[8];
    const float* bq   = (const float*)d_in[9];
    const float* Wk   = (const float*)d_in[10];
    const float* bk   = (const float*)d_in[11];
    const float* Wv   = (const float*)d_in[12];
    const float* bv   = (const float*)d_in[13];
    const float* Wo   = (const float*)d_in[14];
    const float* bo   = (const float*)d_in[15];
    const float* ln_g = (const float*)d_in[16];
    const float* ln_b = (const float*)d_in[17];
    const float* Wh1  = (const float*)d_in[18];
    const float* bh1  = (const float*)d_in[19];
    const float* Wh2  = (const float*)d_in[20];
    const float* bh2  = (const float*)d_in[21];
    float* out = (float*)d_out;

    // workspace layout (256B aligned)
    char* p = (char*)d_ws;
    auto alloc = [&](size_t bytes) {
        char* r = p; p += (bytes + 255) & ~(size_t)255; return r;
    };
    u16*  W1t  = (u16*)alloc((size_t)H_ * D_ * 2);              // 2 MB
    u16*  wv2t = (u16*)alloc((size_t)16 * H_ * 2);              // 64 KB
    float* WW  = (float*)alloc((size_t)H_ * D_ * 4);            // 4 MB
    float* qp  = (float*)alloc(D_ * 4);
    float* wke = (float*)alloc((size_t)D_ * NH_ * 4);
    float* cke = (float*)alloc(NH_ * 4);
    float* ck2 = (float*)alloc(NH_ * 4);
    float* cvv = (float*)alloc(D_ * 4);
    float* spb  = (float*)alloc((size_t)16 * TOT * 8 * 4);      // 33.5 MB score partials
    float* pfin = (float*)alloc((size_t)TOT * 8 * 4);           // 2 MB normalized p
    float* g1   = (float*)alloc((size_t)B_ * 8 * H_ * 4);       // 4 MB
    float* ctxp = (float*)alloc((size_t)B_ * 4 * D_ * 4);       // 512 KB
    float* ybuf = (float*)alloc((size_t)B_ * D_ * 4);
    float* hid  = (float*)alloc((size_t)B_ * H_ * 4);
    u16*  z    = (u16*)alloc((size_t)TOT * D_ * 2);             // 67 MB
    u16*  C1   = (u16*)alloc((size_t)TOT * H_ * 2);             // 268 MB

    // setup / weight folding
    transpose_cvt<<<dim3(H_ / 32, D_ / 32), dim3(32, 8), 0, stream>>>(W1, W1t, D_, H_);
    qp_kernel<<<2, 256, 0, stream>>>(q, Wq, bq, qp);
    wke_kernel<<<16, 256, 0, stream>>>(Wk, bk, qp, wke, cke);
    wv2_kernel<<<64, 256, 0, stream>>>(W2, wke, cke, b2, wv2t, ck2);
    cvv_kernel<<<2, 256, 0, stream>>>(Wv, b2, bv, cvv);
    ww_kernel<<<dim3(8, 32), 256, 0, stream>>>(W2, Wv, WW);

    // phi layer-1 + fused score partials
    embed_kernel<<<TOT / 4, 256, 0, stream>>>(mut_idx, emb, z);
    gemm_bt256<1, 4><<<dim3((TOT / 256) * 16), 512, 0, stream>>>(z, W1t, b1, C1, wv2t, spb, H_, D_);

    // softmax -> single-pass PV -> folded tail
    softmax_kernel<<<B_, 256, 0, stream>>>(spb, ck2, pfin);
    pv_kernel<<<dim3(16, B_), 256, 0, stream>>>(C1, pfin, g1);
    ctx_kernel<<<dim3(4, B_), 256, 0, stream>>>(g1, WW, ctxp);
    pool2_kernel<<<B_, 256, 0, stream>>>(ctxp, cvv, Wo, bo, ln_g, ln_b, ybuf);
    h1_kernel<<<dim3(H_ / 256, B_), 256, 0, stream>>>(ybuf, Wh1, bh1, hid);
    h2_kernel<<<B_, 256, 0, stream>>>(hid, Wh2, bh2, out);
}

// Round 6
// 766.416 us; speedup vs baseline: 1.2498x; 1.0781x over previous
//
#include <hip/hip_runtime.h>
#include <hip/hip_bf16.h>

using u16 = unsigned short;
typedef __bf16 bf16x8_t __attribute__((ext_vector_type(8)));
typedef float    f32x4  __attribute__((ext_vector_type(4)));
typedef unsigned short u16x8 __attribute__((ext_vector_type(8)));

#define B_  64
#define L_  1024
#define TOT 65536
#define D_  512
#define H_  2048
#define NH_ 8

__device__ __forceinline__ float b2f(u16 x) {
    union { unsigned int i; float f; } v; v.i = ((unsigned int)x) << 16; return v.f;
}
__device__ __forceinline__ u16 f2b(float f) {
    union { float f; unsigned int i; } v; v.f = f;
    unsigned int i = v.i;
    unsigned int r = i + 0x7FFFu + ((i >> 16) & 1u);   // RNE
    return (u16)(r >> 16);
}

// ---------------- zero sfull (re-zeroed every launch before gemm atomics)
__global__ __launch_bounds__(256) void zero_kernel(float* __restrict__ p) {
    ((float4*)p)[blockIdx.x * 256 + threadIdx.x] = float4{0.f, 0.f, 0.f, 0.f};
}

// ---------------- transpose + fp32->bf16 convert:  in[R][C] f32 -> out[C][R] bf16
__global__ __launch_bounds__(256) void transpose_cvt(const float* __restrict__ in,
                                                     u16* __restrict__ out, int R, int C) {
    __shared__ float tile[32][33];
    int c0 = blockIdx.x * 32, r0 = blockIdx.y * 32;
    int tx = threadIdx.x, ty = threadIdx.y;
    #pragma unroll
    for (int i = 0; i < 4; ++i)
        tile[ty + 8 * i][tx] = in[(size_t)(r0 + ty + 8 * i) * C + c0 + tx];
    __syncthreads();
    #pragma unroll
    for (int i = 0; i < 4; ++i)
        out[(size_t)(c0 + ty + 8 * i) * R + r0 + tx] = f2b(tile[tx][ty + 8 * i]);
}

// ---------------- qp = q @ Wq + bq   (16 blocks x 32 j, 8-way k-split, LDS reduce)
__global__ __launch_bounds__(256) void qp_kernel(const float* __restrict__ q,
                                                 const float* __restrict__ Wq,
                                                 const float* __restrict__ bq,
                                                 float* __restrict__ qp) {
    __shared__ float qs[512];
    __shared__ float red[8][32];
    int tid = threadIdx.x;
    qs[tid] = q[tid]; qs[tid + 256] = q[tid + 256];
    __syncthreads();
    int jl = tid & 31, ks = tid >> 5;
    int j = blockIdx.x * 32 + jl;
    float acc = 0.f;
    for (int d = ks * 64; d < ks * 64 + 64; ++d) acc += qs[d] * Wq[(size_t)d * 512 + j];
    red[ks][jl] = acc;
    __syncthreads();
    if (tid < 32) {
        float s = bq[blockIdx.x * 32 + tid];
        #pragma unroll
        for (int k = 0; k < 8; ++k) s += red[k][tid];
        qp[blockIdx.x * 32 + tid] = s;
    }
}

// ---------------- wke[d][h] = 0.125*sum_j Wk[d,h*64+j]*qp[h*64+j];  cke[h] from bk
__global__ __launch_bounds__(256) void wke_kernel(const float* __restrict__ Wk,
                                                  const float* __restrict__ bk,
                                                  const float* __restrict__ qp,
                                                  float* __restrict__ wke,
                                                  float* __restrict__ cke) {
    __shared__ float qs[512];
    int tid = threadIdx.x;
    qs[tid] = qp[tid]; qs[tid + 256] = qp[tid + 256];
    __syncthreads();
    int d = blockIdx.x * 32 + (tid >> 3);
    int h = tid & 7;
    float s = 0.f;
    for (int j = 0; j < 64; ++j) s += Wk[(size_t)d * 512 + h * 64 + j] * qs[h * 64 + j];
    wke[d * 8 + h] = 0.125f * s;
    if (blockIdx.x == 0 && tid < 8) {
        float c = 0.f;
        for (int j = 0; j < 64; ++j) c += bk[tid * 64 + j] * qs[tid * 64 + j];
        cke[tid] = 0.125f * c;
    }
}

// ---------------- wv2t[h][k] = bf16( sum_d W2[k][d]*wke[d][h] ), rows 8..15 zero.
// ck2[h] = sum_d b2[d]*wke[d][h] + cke[h]
__global__ __launch_bounds__(256) void wv2_kernel(const float* __restrict__ W2,
                                                  const float* __restrict__ wke,
                                                  const float* __restrict__ cke,
                                                  const float* __restrict__ b2,
                                                  u16* __restrict__ wv2t,
                                                  float* __restrict__ ck2) {
    __shared__ float wk[512 * 8];
    int tid = threadIdx.x;
    for (int i = tid; i < 4096; i += 256) wk[i] = wke[i];
    __syncthreads();
    int k = blockIdx.x * 32 + (tid >> 3);
    int h = tid & 7;
    float s = 0.f;
    const float* row = W2 + (size_t)k * 512;
    for (int d = 0; d < 512; ++d) s += row[d] * wk[d * 8 + h];
    wv2t[(size_t)h * 2048 + k] = f2b(s);
    wv2t[(size_t)(h + 8) * 2048 + k] = 0;
    if (blockIdx.x == 0 && tid < 8) {
        float c = 0.f;
        for (int d = 0; d < 512; ++d) c += b2[d] * wk[d * 8 + tid];
        ck2[tid] = c + cke[tid];
    }
}

// ---------------- cvv[e] = sum_d b2[d]*Wv[d][e] + bv[e]  (16 blocks, 8-way k-split)
__global__ __launch_bounds__(256) void cvv_kernel(const float* __restrict__ Wv,
                                                  const float* __restrict__ b2,
                                                  const float* __restrict__ bv,
                                                  float* __restrict__ cvv) {
    __shared__ float bs[512];
    __shared__ float red[8][32];
    int tid = threadIdx.x;
    bs[tid] = b2[tid]; bs[tid + 256] = b2[tid + 256];
    __syncthreads();
    int el = tid & 31, ks = tid >> 5;
    int e = blockIdx.x * 32 + el;
    float acc = 0.f;
    for (int d = ks * 64; d < ks * 64 + 64; ++d) acc += bs[d] * Wv[(size_t)d * 512 + e];
    red[ks][el] = acc;
    __syncthreads();
    if (tid < 32) {
        float s = bv[blockIdx.x * 32 + tid];
        #pragma unroll
        for (int k = 0; k < 8; ++k) s += red[k][tid];
        cvv[blockIdx.x * 32 + tid] = s;
    }
}

// ---------------- WW[2048][512] = W2[2048][512] @ Wv[512][512]  (fp32 tiled)
__global__ __launch_bounds__(256) void ww_kernel(const float* __restrict__ W2,
                                                 const float* __restrict__ Wv,
                                                 float* __restrict__ WW) {
    __shared__ float As[64][65];
    __shared__ float Bs[64][65];
    const int m0 = blockIdx.y * 64, n0 = blockIdx.x * 64;
    const int tid = threadIdx.x;
    const int tx = tid & 15, ty = tid >> 4;
    float acc[4][4] = {};
    for (int k0 = 0; k0 < 512; k0 += 64) {
        for (int i = tid; i < 4096; i += 256) {
            int r = i >> 6, c = i & 63;
            As[r][c] = W2[(size_t)(m0 + r) * 512 + k0 + c];
            Bs[r][c] = Wv[(size_t)(k0 + r) * 512 + n0 + c];
        }
        __syncthreads();
        for (int kk = 0; kk < 64; ++kk) {
            float a[4], b[4];
            #pragma unroll
            for (int i = 0; i < 4; ++i) a[i] = As[ty * 4 + i][kk];
            #pragma unroll
            for (int j = 0; j < 4; ++j) b[j] = Bs[kk][tx * 4 + j];
            #pragma unroll
            for (int i = 0; i < 4; ++i)
                #pragma unroll
                for (int j = 0; j < 4; ++j) acc[i][j] += a[i] * b[j];
        }
        __syncthreads();
    }
    #pragma unroll
    for (int i = 0; i < 4; ++i)
        #pragma unroll
        for (int j = 0; j < 4; ++j)
            WW[(size_t)(m0 + ty * 4 + i) * 512 + n0 + tx * 4 + j] = acc[i][j];
}

// ---------------- gather emb rows -> bf16 z
__global__ __launch_bounds__(256) void embed_kernel(const int* __restrict__ idx,
                                                    const float* __restrict__ emb,
                                                    u16* __restrict__ z) {
    int u = blockIdx.x * 256 + threadIdx.x;   // one unit = 8 elements
    int t = u >> 6;
    int d0 = (u & 63) * 8;
    int row = idx[t];
    const float4* src = (const float4*)(emb + (size_t)row * 512 + d0);
    float4 a = src[0], b = src[1];
    u16x8 o;
    o[0] = f2b(a.x); o[1] = f2b(a.y); o[2] = f2b(a.z); o[3] = f2b(a.w);
    o[4] = f2b(b.x); o[5] = f2b(b.y); o[6] = f2b(b.z); o[7] = f2b(b.w);
    *(u16x8*)(z + (size_t)t * 512 + d0) = o;
}

// ---------------- bf16 GEMM 256x128, BK=64, 8 waves (round-0 structure)
// + fused score epilogue; R6: score partials go via atomicAdd into sfull[token][8]
// (2 MB, L2-resident) instead of a 33.5 MB spb partial buffer.
template <int RELU, int LNT>
__global__ __launch_bounds__(512) void gemm_bt256(const u16* __restrict__ A,
                                                  const u16* __restrict__ Bt,
                                                  const float* __restrict__ bias,
                                                  u16* __restrict__ C,
                                                  const u16* __restrict__ wv2t,
                                                  float* __restrict__ sfull,
                                                  int N, int K) {
    __shared__ __align__(16) u16 As[256 * 64];
    __shared__ __align__(16) u16 Bs[128 * 64];
    const int tid = threadIdx.x;
    const int id = blockIdx.x;
    const int xcd = id & 7, s = id >> 3;
    const int n_idx = s & ((1 << LNT) - 1);
    const int m_idx = xcd + 8 * (s >> LNT);
    const int m0 = m_idx * 256, n0 = n_idx * 128;
    const int lane = tid & 63, quad = lane >> 4, l15 = lane & 15;
    const int wave = tid >> 6, wm = wave >> 1, wn = wave & 1;

    f32x4 acc[4][4] = {};

    const int nK = K >> 6;
    for (int kt = 0; kt < nK; ++kt) {
        __syncthreads();
        const int kb = kt * 64;
        #pragma unroll
        for (int r = 0; r < 4; ++r) {
            int u = tid + r * 512;
            int row = u >> 3;
            int cg = (u & 7) ^ (row & 7);
            const u16* ga = A + (size_t)(m0 + row) * K + kb + cg * 8;
            __builtin_amdgcn_global_load_lds((const __attribute__((address_space(1))) void*)ga,
                                             (__attribute__((address_space(3))) void*)(&As[u * 8]),
                                             16, 0, 0);
        }
        #pragma unroll
        for (int r = 0; r < 2; ++r) {
            int u = tid + r * 512;
            int row = u >> 3;
            int cg = (u & 7) ^ (row & 7);
            const u16* gb = Bt + (size_t)(n0 + row) * K + kb + cg * 8;
            __builtin_amdgcn_global_load_lds((const __attribute__((address_space(1))) void*)gb,
                                             (__attribute__((address_space(3))) void*)(&Bs[u * 8]),
                                             16, 0, 0);
        }
        __syncthreads();
        #pragma unroll
        for (int ks = 0; ks < 2; ++ks) {
            bf16x8_t af[4], bfr[4];
            #pragma unroll
            for (int mt = 0; mt < 4; ++mt) {
                int row = wm * 64 + mt * 16 + l15;
                int g = (ks * 4 + quad) ^ (row & 7);
                af[mt] = *(const bf16x8_t*)&As[row * 64 + g * 8];
            }
            #pragma unroll
            for (int nt = 0; nt < 4; ++nt) {
                int row = wn * 64 + nt * 16 + l15;
                int g = (ks * 4 + quad) ^ (row & 7);
                bfr[nt] = *(const bf16x8_t*)&Bs[row * 64 + g * 8];
            }
            #pragma unroll
            for (int mt = 0; mt < 4; ++mt)
                #pragma unroll
                for (int nt = 0; nt < 4; ++nt)
                    acc[mt][nt] = __builtin_amdgcn_mfma_f32_16x16x32_bf16(af[mt], bfr[nt],
                                                                          acc[mt][nt], 0, 0, 0);
        }
    }

    float bvv[4];
    #pragma unroll
    for (int nt = 0; nt < 4; ++nt) bvv[nt] = bias[n0 + wn * 64 + nt * 16 + l15];
    #pragma unroll
    for (int mt = 0; mt < 4; ++mt)
        #pragma unroll
        for (int nt = 0; nt < 4; ++nt)
            #pragma unroll
            for (int r = 0; r < 4; ++r) {
                int row = m0 + wm * 64 + mt * 16 + quad * 4 + r;
                int col = n0 + wn * 64 + nt * 16 + l15;
                float v = acc[mt][nt][r] + bvv[nt];
                if (RELU) v = fmaxf(v, 0.f);
                C[(size_t)row * N + col] = f2b(v);
            }

    // ---- fused score partials: atomicAdd( C_tile @ wv2t_slice^T ) into sfull[token][h]
    __syncthreads();     // all main-loop LDS reads finished in every wave
    f32x4 accs[2] = {};
    #pragma unroll
    for (int p = 0; p < 2; ++p) {
        if (wn == p) {   // this half's columns live in these 4 waves
            #pragma unroll
            for (int mt = 0; mt < 4; ++mt)
                #pragma unroll
                for (int nt = 0; nt < 4; ++nt)
                    #pragma unroll
                    for (int r = 0; r < 4; ++r) {
                        int row = wm * 64 + mt * 16 + quad * 4 + r;
                        int c   = nt * 16 + l15;
                        float v = fmaxf(acc[mt][nt][r] + bvv[nt], 0.f);
                        As[row * 64 + (((c >> 3) ^ (row & 7)) << 3) + (c & 7)] = f2b(v);
                    }
        }
        if (tid < 128) { // wv2t slice: 16 rows x 64 cols, same swizzle
            int hrow = tid >> 3, cg = tid & 7;
            u16x8 v = *(const u16x8*)&wv2t[(size_t)hrow * 2048 + n0 + p * 64 + cg * 8];
            *(u16x8*)&Bs[hrow * 64 + ((cg ^ (hrow & 7)) << 3)] = v;
        }
        __syncthreads();
        #pragma unroll
        for (int m2 = 0; m2 < 2; ++m2) {
            int arow = (wave * 2 + m2) * 16 + l15;
            #pragma unroll
            for (int ks = 0; ks < 2; ++ks) {
                bf16x8_t av = *(const bf16x8_t*)&As[arow * 64 + (((ks * 4 + quad) ^ (arow & 7)) << 3)];
                bf16x8_t bv = *(const bf16x8_t*)&Bs[l15 * 64 + (((ks * 4 + quad) ^ (l15 & 7)) << 3)];
                accs[m2] = __builtin_amdgcn_mfma_f32_16x16x32_bf16(av, bv, accs[m2], 0, 0, 0);
            }
        }
        __syncthreads();
    }
    if (l15 < 8) {
        #pragma unroll
        for (int m2 = 0; m2 < 2; ++m2)
            #pragma unroll
            for (int r = 0; r < 4; ++r) {
                int row = m0 + (wave * 2 + m2) * 16 + quad * 4 + r;
                atomicAdd(&sfull[(size_t)row * 8 + l15], accs[m2][r]);
            }
    }
}

// ---------------- softmax over full set: s = sfull + ck2; p = softmax_l(s)
__global__ __launch_bounds__(256) void softmax_kernel(const float* __restrict__ sfull,
                                                      const float* __restrict__ ck2,
                                                      float* __restrict__ pfin) {
    __shared__ float ps[1024 * 8];   // 32 KB
    __shared__ float red[32 * 8];
    __shared__ float mh[8], dn[8];
    const int b = blockIdx.x, tid = threadIdx.x;
    for (int i = tid; i < 8192; i += 256) {
        int h = i & 7;
        ps[i] = sfull[(size_t)b * 8192 + i] + ck2[h];
    }
    __syncthreads();
    {
        int slot = tid >> 3, h = tid & 7;
        float m = -1e30f;
        for (int i = 0; i < 32; ++i) m = fmaxf(m, ps[(slot + 32 * i) * 8 + h]);
        red[slot * 8 + h] = m;
    }
    __syncthreads();
    if (tid < 8) {
        float m = -1e30f;
        for (int s2 = 0; s2 < 32; ++s2) m = fmaxf(m, red[s2 * 8 + tid]);
        mh[tid] = m;
    }
    __syncthreads();
    for (int i = tid; i < 8192; i += 256) {
        int h = i & 7;
        ps[i] = __expf(ps[i] - mh[h]);
    }
    __syncthreads();
    {
        int slot = tid >> 3, h = tid & 7;
        float sum = 0.f;
        for (int i = 0; i < 32; ++i) sum += ps[(slot + 32 * i) * 8 + h];
        red[slot * 8 + h] = sum;
    }
    __syncthreads();
    if (tid < 8) {
        float sum = 0.f;
        for (int s2 = 0; s2 < 32; ++s2) sum += red[s2 * 8 + tid];
        dn[tid] = 1.f / sum;
    }
    __syncthreads();
    for (int i = tid; i < 8192; i += 256) {
        int h = i & 7;
        pfin[(size_t)b * 8192 + i] = ps[i] * dn[h];
    }
}

// ---------------- pv: g1[b][h][k] = sum_l p[l][h] * C1[b*1024+l][k]  (one C1 pass)
__global__ __launch_bounds__(256) void pv_kernel(const u16* __restrict__ C1,
                                                 const float* __restrict__ pfin,
                                                 float* __restrict__ g1) {
    __shared__ float psl[1024 * 8];       // 32 KB
    __shared__ float red[4 * 8 * 128];    // 16 KB
    const int kc = blockIdx.x, b = blockIdx.y, tid = threadIdx.x;
    const int lane = tid & 63, wave = tid >> 6;
    const int colgrp = tid & 15, slot = tid >> 4;   // 16 col-groups x 16 l-slots
    for (int i = tid; i < 8192; i += 256)
        psl[i] = pfin[(size_t)b * 8192 + i];
    __syncthreads();
    const u16* base = C1 + (size_t)(b * 1024 + slot) * 2048 + kc * 128 + colgrp * 8;
    float a[8][8] = {};   // [h][j]
    for (int i = 0; i < 64; ++i) {        // l = slot + 16*i
        int l = slot + 16 * i;
        u16x8 v = *(const u16x8*)(base + (size_t)16 * i * 2048);
        float4 p0 = *(const float4*)&psl[l * 8];
        float4 p1 = *(const float4*)&psl[l * 8 + 4];
        float pv8[8] = {p0.x, p0.y, p0.z, p0.w, p1.x, p1.y, p1.z, p1.w};
        #pragma unroll
        for (int j = 0; j < 8; ++j) {
            float hf = b2f(v[j]);
            #pragma unroll
            for (int h = 0; h < 8; ++h) a[h][j] += pv8[h] * hf;
        }
    }
    // reduce the 4 in-wave slots (lane bits 4-5), then 4 waves via LDS
    #pragma unroll
    for (int h = 0; h < 8; ++h)
        #pragma unroll
        for (int j = 0; j < 8; ++j) {
            a[h][j] += __shfl_xor(a[h][j], 16, 64);
            a[h][j] += __shfl_xor(a[h][j], 32, 64);
        }
    if (lane < 16) {
        #pragma unroll
        for (int h = 0; h < 8; ++h)
            #pragma unroll
            for (int j = 0; j < 8; ++j)
                red[(wave * 8 + h) * 128 + lane * 8 + j] = a[h][j];
    }
    __syncthreads();
    for (int i = tid; i < 1024; i += 256) {
        int h = i >> 7, cj = i & 127;
        float sv = red[(0 * 8 + h) * 128 + cj] + red[(1 * 8 + h) * 128 + cj]
                 + red[(2 * 8 + h) * 128 + cj] + red[(3 * 8 + h) * 128 + cj];
        g1[((size_t)b * 8 + h) * 2048 + kc * 128 + cj] = sv;
    }
}

// ---------------- ctx partials: ctxp = g1 @ WW (kc slice)
__global__ __launch_bounds__(256) void ctx_kernel(const float* __restrict__ g1,
                                                  const float* __restrict__ WW,
                                                  float* __restrict__ ctxp) {
    __shared__ float g1c[8 * 512];
    const int kc = blockIdx.x, b = blockIdx.y, tid = threadIdx.x;
    for (int i = tid; i < 4096; i += 256) {
        int hh = i >> 9, k = i & 511;
        g1c[hh * 512 + k] = g1[((size_t)b * 8 + hh) * 2048 + kc * 512 + k];
    }
    __syncthreads();
    const int e1 = tid, e2 = tid + 256;
    const int h1 = e1 >> 6, h2 = e2 >> 6;
    float a1 = 0.f, a2 = 0.f;
    for (int k = 0; k < 512; k += 4) {
        float4 g1v = *(const float4*)&g1c[h1 * 512 + k];
        float4 g2v = *(const float4*)&g1c[h2 * 512 + k];
        const float* wr = WW + (size_t)(kc * 512 + k) * 512;
        a1 += g1v.x * wr[e1] + g1v.y * wr[512 + e1] + g1v.z * wr[1024 + e1] + g1v.w * wr[1536 + e1];
        a2 += g2v.x * wr[e2] + g2v.y * wr[512 + e2] + g2v.z * wr[1024 + e2] + g2v.w * wr[1536 + e2];
    }
    ctxp[((size_t)b * 4 + kc) * 512 + e1] = a1;
    ctxp[((size_t)b * 4 + kc) * 512 + e2] = a2;
}

// ---------------- per-set: ctx fold + pooled = ctx@Wo + bo; LN -> y
__global__ __launch_bounds__(256) void pool2_kernel(const float* __restrict__ ctxp,
                                                    const float* __restrict__ cvv,
                                                    const float* __restrict__ Wo,
                                                    const float* __restrict__ bo,
                                                    const float* __restrict__ g,
                                                    const float* __restrict__ lb,
                                                    float* __restrict__ y) {
    __shared__ float ctx[512];
    __shared__ float red[8];
    __shared__ float stats[2];
    const int b = blockIdx.x, tid = threadIdx.x;
    for (int i = tid; i < 512; i += 256) {
        float s = cvv[i];
        #pragma unroll
        for (int kc = 0; kc < 4; ++kc) s += ctxp[((size_t)b * 4 + kc) * 512 + i];
        ctx[i] = s;
    }
    __syncthreads();
    float pv[2]; float psum = 0.f, psq = 0.f;
    #pragma unroll
    for (int ph = 0; ph < 2; ++ph) {
        int e2 = tid + ph * 256;
        float acc = bo[e2];
        for (int ee = 0; ee < 512; ++ee) acc += ctx[ee] * Wo[(size_t)ee * 512 + e2];
        pv[ph] = acc; psum += acc; psq += acc * acc;
    }
    for (int off = 32; off; off >>= 1) { psum += __shfl_xor(psum, off, 64); psq += __shfl_xor(psq, off, 64); }
    const int w = tid >> 6, lane = tid & 63;
    if (lane == 0) { red[w] = psum; red[4 + w] = psq; }
    __syncthreads();
    if (tid == 0) {
        float s = red[0] + red[1] + red[2] + red[3];
        float q2 = red[4] + red[5] + red[6] + red[7];
        float mu = s / 512.f;
        float var = q2 / 512.f - mu * mu;
        stats[0] = mu; stats[1] = 1.f / sqrtf(var + 1e-5f);
    }
    __syncthreads();
    #pragma unroll
    for (int ph = 0; ph < 2; ++ph) {
        int e2 = tid + ph * 256;
        y[(size_t)b * 512 + e2] = (pv[ph] - stats[0]) * stats[1] * g[e2] + lb[e2];
    }
}

// ---------------- head MLP layer 1: hid = relu(y@Wh1 + bh1)
__global__ __launch_bounds__(256) void h1_kernel(const float* __restrict__ y,
                                                 const float* __restrict__ Wh1,
                                                 const float* __restrict__ bh1,
                                                 float* __restrict__ hid) {
    __shared__ float ys[512];
    const int b = blockIdx.y, tid = threadIdx.x;
    ys[tid] = y[(size_t)b * 512 + tid];
    ys[tid + 256] = y[(size_t)b * 512 + tid + 256];
    __syncthreads();
    int j = blockIdx.x * 256 + tid;
    float acc = bh1[j];
    for (int dd = 0; dd < 512; ++dd) acc += ys[dd] * Wh1[(size_t)dd * 2048 + j];
    hid[(size_t)b * 2048 + j] = fmaxf(acc, 0.f);
}

// ---------------- head MLP layer 2: logits = hid@Wh2 + bh2
__global__ __launch_bounds__(256) void h2_kernel(const float* __restrict__ hid,
                                                 const float* __restrict__ Wh2,
                                                 const float* __restrict__ bh2,
                                                 float* __restrict__ out) {
    __shared__ float red[4];
    const int b = blockIdx.x, tid = threadIdx.x;
    float s = 0.f;
    for (int j = tid; j < 2048; j += 256) s += hid[(size_t)b * 2048 + j] * Wh2[j];
    for (int off = 32; off; off >>= 1) s += __shfl_xor(s, off, 64);
    const int w = tid >> 6, lane = tid & 63;
    if (lane == 0) red[w] = s;
    __syncthreads();
    if (tid == 0) out[b] = red[0] + red[1] + red[2] + red[3] + bh2[0];
}

extern "C" void kernel_launch(void* const* d_in, const int* in_sizes, int n_in,
                              void* d_out, int out_size, void* d_ws, size_t ws_size,
                              hipStream_t stream) {
    const int*   mut_idx = (const int*)d_in[0];
    const float* emb  = (const float*)d_in[2];
    const float* W1   = (const float*)d_in[3];
    const float* b1   = (const float*)d_in[4];
    const float* W2   = (const float*)d_in[5];
    const float* b2   = (const float*)d_in[6];
    const float* q    = (const float*)d_in[7];
    const float* Wq   = (const float*)d_in[8];
    const float* bq   = (const float*)d_in[9];
    const float* Wk   = (const float*)d_in[10];
    const float* bk   = (const float*)d_in[11];
    const float* Wv   = (const float*)d_in[12];
    const float* bv   = (const float*)d_in[13];
    const float* Wo   = (const float*)d_in[14];
    const float* bo   = (const float*)d_in[15];
    const float* ln_g = (const float*)d_in[16];
    const float* ln_b = (const float*)d_in[17];
    const float* Wh1  = (const float*)d_in[18];
    const float* bh1  = (const float*)d_in[19];
    const float* Wh2  = (const float*)d_in[20];
    const float* bh2  = (const float*)d_in[21];
    float* out = (float*)d_out;

    // workspace layout (256B aligned)
    char* p = (char*)d_ws;
    auto alloc = [&](size_t bytes) {
        char* r = p; p += (bytes + 255) & ~(size_t)255; return r;
    };
    u16*  W1t  = (u16*)alloc((size_t)H_ * D_ * 2);              // 2 MB
    u16*  wv2t = (u16*)alloc((size_t)16 * H_ * 2);              // 64 KB
    float* WW  = (float*)alloc((size_t)H_ * D_ * 4);            // 4 MB
    float* qp  = (float*)alloc(D_ * 4);
    float* wke = (float*)alloc((size_t)D_ * NH_ * 4);
    float* cke = (float*)alloc(NH_ * 4);
    float* ck2 = (float*)alloc(NH_ * 4);
    float* cvv = (float*)alloc(D_ * 4);
    float* sfull = (float*)alloc((size_t)TOT * 8 * 4);          // 2 MB score accumulator
    float* pfin = (float*)alloc((size_t)TOT * 8 * 4);           // 2 MB normalized p
    float* g1   = (float*)alloc((size_t)B_ * 8 * H_ * 4);       // 4 MB
    float* ctxp = (float*)alloc((size_t)B_ * 4 * D_ * 4);       // 512 KB
    float* ybuf = (float*)alloc((size_t)B_ * D_ * 4);
    float* hid  = (float*)alloc((size_t)B_ * H_ * 4);
    u16*  z    = (u16*)alloc((size_t)TOT * D_ * 2);             // 67 MB
    u16*  C1   = (u16*)alloc((size_t)TOT * H_ * 2);             // 268 MB

    // setup / weight folding (+ zero the atomic score accumulator)
    zero_kernel<<<TOT * 8 / 1024, 256, 0, stream>>>(sfull);
    transpose_cvt<<<dim3(H_ / 32, D_ / 32), dim3(32, 8), 0, stream>>>(W1, W1t, D_, H_);
    qp_kernel<<<16, 256, 0, stream>>>(q, Wq, bq, qp);
    wke_kernel<<<16, 256, 0, stream>>>(Wk, bk, qp, wke, cke);
    wv2_kernel<<<64, 256, 0, stream>>>(W2, wke, cke, b2, wv2t, ck2);
    cvv_kernel<<<16, 256, 0, stream>>>(Wv, b2, bv, cvv);
    ww_kernel<<<dim3(8, 32), 256, 0, stream>>>(W2, Wv, WW);

    // phi layer-1 + fused score partials (atomic)
    embed_kernel<<<TOT / 4, 256, 0, stream>>>(mut_idx, emb, z);
    gemm_bt256<1, 4><<<dim3((TOT / 256) * 16), 512, 0, stream>>>(z, W1t, b1, C1, wv2t, sfull, H_, D_);

    // softmax -> single-pass PV -> folded tail
    softmax_kernel<<<B_, 256, 0, stream>>>(sfull, ck2, pfin);
    pv_kernel<<<dim3(16, B_), 256, 0, stream>>>(C1, pfin, g1);
    ctx_kernel<<<dim3(4, B_), 256, 0, stream>>>(g1, WW, ctxp);
    pool2_kernel<<<B_, 256, 0, stream>>>(ctxp, cvv, Wo, bo, ln_g, ln_b, ybuf);
    h1_kernel<<<dim3(H_ / 256, B_), 256, 0, stream>>>(ybuf, Wh1, bh1, hid);
    h2_kernel<<<B_, 256, 0, stream>>>(hid, Wh2, bh2, out);
}

// Round 8
// 754.122 us; speedup vs baseline: 1.2702x; 1.0163x over previous
//
#include <hip/hip_runtime.h>
#include <hip/hip_bf16.h>

using u16 = unsigned short;
typedef __bf16 bf16x8_t __attribute__((ext_vector_type(8)));
typedef float    f32x4  __attribute__((ext_vector_type(4)));
typedef unsigned short u16x8 __attribute__((ext_vector_type(8)));

#define B_  64
#define L_  1024
#define TOT 65536
#define D_  512
#define H_  2048
#define NH_ 8

__device__ __forceinline__ float b2f(u16 x) {
    union { unsigned int i; float f; } v; v.i = ((unsigned int)x) << 16; return v.f;
}
__device__ __forceinline__ u16 f2b(float f) {
    union { float f; unsigned int i; } v; v.f = f;
    unsigned int i = v.i;
    unsigned int r = i + 0x7FFFu + ((i >> 16) & 1u);   // RNE
    return (u16)(r >> 16);
}

// ---------------- zero sfull (re-zeroed every launch before gemm atomics)
__global__ __launch_bounds__(256) void zero_kernel(float* __restrict__ p) {
    ((float4*)p)[blockIdx.x * 256 + threadIdx.x] = float4{0.f, 0.f, 0.f, 0.f};
}

// ---------------- transpose + fp32->bf16 convert:  in[R][C] f32 -> out[C][R] bf16
__global__ __launch_bounds__(256) void transpose_cvt(const float* __restrict__ in,
                                                     u16* __restrict__ out, int R, int C) {
    __shared__ float tile[32][33];
    int c0 = blockIdx.x * 32, r0 = blockIdx.y * 32;
    int tx = threadIdx.x, ty = threadIdx.y;
    #pragma unroll
    for (int i = 0; i < 4; ++i)
        tile[ty + 8 * i][tx] = in[(size_t)(r0 + ty + 8 * i) * C + c0 + tx];
    __syncthreads();
    #pragma unroll
    for (int i = 0; i < 4; ++i)
        out[(size_t)(c0 + ty + 8 * i) * R + r0 + tx] = f2b(tile[tx][ty + 8 * i]);
}

// ---------------- qp = q @ Wq + bq   (16 blocks x 32 j, 8-way k-split, LDS reduce)
__global__ __launch_bounds__(256) void qp_kernel(const float* __restrict__ q,
                                                 const float* __restrict__ Wq,
                                                 const float* __restrict__ bq,
                                                 float* __restrict__ qp) {
    __shared__ float qs[512];
    __shared__ float red[8][32];
    int tid = threadIdx.x;
    qs[tid] = q[tid]; qs[tid + 256] = q[tid + 256];
    __syncthreads();
    int jl = tid & 31, ks = tid >> 5;
    int j = blockIdx.x * 32 + jl;
    float acc = 0.f;
    for (int d = ks * 64; d < ks * 64 + 64; ++d) acc += qs[d] * Wq[(size_t)d * 512 + j];
    red[ks][jl] = acc;
    __syncthreads();
    if (tid < 32) {
        float s = bq[blockIdx.x * 32 + tid];
        #pragma unroll
        for (int k = 0; k < 8; ++k) s += red[k][tid];
        qp[blockIdx.x * 32 + tid] = s;
    }
}

// ---------------- wke[d][h] = 0.125*sum_j Wk[d,h*64+j]*qp[h*64+j];  cke[h] from bk
__global__ __launch_bounds__(256) void wke_kernel(const float* __restrict__ Wk,
                                                  const float* __restrict__ bk,
                                                  const float* __restrict__ qp,
                                                  float* __restrict__ wke,
                                                  float* __restrict__ cke) {
    __shared__ float qs[512];
    int tid = threadIdx.x;
    qs[tid] = qp[tid]; qs[tid + 256] = qp[tid + 256];
    __syncthreads();
    int d = blockIdx.x * 32 + (tid >> 3);
    int h = tid & 7;
    float s = 0.f;
    for (int j = 0; j < 64; ++j) s += Wk[(size_t)d * 512 + h * 64 + j] * qs[h * 64 + j];
    wke[d * 8 + h] = 0.125f * s;
    if (blockIdx.x == 0 && tid < 8) {
        float c = 0.f;
        for (int j = 0; j < 64; ++j) c += bk[tid * 64 + j] * qs[tid * 64 + j];
        cke[tid] = 0.125f * c;
    }
}

// ---------------- wv2t[h][k] = bf16( sum_d W2[k][d]*wke[d][h] ), rows 8..15 zero.
// ck2[h] = sum_d b2[d]*wke[d][h] + cke[h]
__global__ __launch_bounds__(256) void wv2_kernel(const float* __restrict__ W2,
                                                  const float* __restrict__ wke,
                                                  const float* __restrict__ cke,
                                                  const float* __restrict__ b2,
                                                  u16* __restrict__ wv2t,
                                                  float* __restrict__ ck2) {
    __shared__ float wk[512 * 8];
    int tid = threadIdx.x;
    for (int i = tid; i < 4096; i += 256) wk[i] = wke[i];
    __syncthreads();
    int k = blockIdx.x * 32 + (tid >> 3);
    int h = tid & 7;
    float s = 0.f;
    const float* row = W2 + (size_t)k * 512;
    for (int d = 0; d < 512; ++d) s += row[d] * wk[d * 8 + h];
    wv2t[(size_t)h * 2048 + k] = f2b(s);
    wv2t[(size_t)(h + 8) * 2048 + k] = 0;
    if (blockIdx.x == 0 && tid < 8) {
        float c = 0.f;
        for (int d = 0; d < 512; ++d) c += b2[d] * wk[d * 8 + tid];
        ck2[tid] = c + cke[tid];
    }
}

// ---------------- cvv[e] = sum_d b2[d]*Wv[d][e] + bv[e]  (16 blocks, 8-way k-split)
__global__ __launch_bounds__(256) void cvv_kernel(const float* __restrict__ Wv,
                                                  const float* __restrict__ b2,
                                                  const float* __restrict__ bv,
                                                  float* __restrict__ cvv) {
    __shared__ float bs[512];
    __shared__ float red[8][32];
    int tid = threadIdx.x;
    bs[tid] = b2[tid]; bs[tid + 256] = b2[tid + 256];
    __syncthreads();
    int el = tid & 31, ks = tid >> 5;
    int e = blockIdx.x * 32 + el;
    float acc = 0.f;
    for (int d = ks * 64; d < ks * 64 + 64; ++d) acc += bs[d] * Wv[(size_t)d * 512 + e];
    red[ks][el] = acc;
    __syncthreads();
    if (tid < 32) {
        float s = bv[blockIdx.x * 32 + tid];
        #pragma unroll
        for (int k = 0; k < 8; ++k) s += red[k][tid];
        cvv[blockIdx.x * 32 + tid] = s;
    }
}

// ---------------- WW[2048][512] = W2[2048][512] @ Wv[512][512]  (fp32 tiled)
__global__ __launch_bounds__(256) void ww_kernel(const float* __restrict__ W2,
                                                 const float* __restrict__ Wv,
                                                 float* __restrict__ WW) {
    __shared__ float As[64][65];
    __shared__ float Bs[64][65];
    const int m0 = blockIdx.y * 64, n0 = blockIdx.x * 64;
    const int tid = threadIdx.x;
    const int tx = tid & 15, ty = tid >> 4;
    float acc[4][4] = {};
    for (int k0 = 0; k0 < 512; k0 += 64) {
        for (int i = tid; i < 4096; i += 256) {
            int r = i >> 6, c = i & 63;
            As[r][c] = W2[(size_t)(m0 + r) * 512 + k0 + c];
            Bs[r][c] = Wv[(size_t)(k0 + r) * 512 + n0 + c];
        }
        __syncthreads();
        for (int kk = 0; kk < 64; ++kk) {
            float a[4], b[4];
            #pragma unroll
            for (int i = 0; i < 4; ++i) a[i] = As[ty * 4 + i][kk];
            #pragma unroll
            for (int j = 0; j < 4; ++j) b[j] = Bs[kk][tx * 4 + j];
            #pragma unroll
            for (int i = 0; i < 4; ++i)
                #pragma unroll
                for (int j = 0; j < 4; ++j) acc[i][j] += a[i] * b[j];
        }
        __syncthreads();
    }
    #pragma unroll
    for (int i = 0; i < 4; ++i)
        #pragma unroll
        for (int j = 0; j < 4; ++j)
            WW[(size_t)(m0 + ty * 4 + i) * 512 + n0 + tx * 4 + j] = acc[i][j];
}

// ---------------- gather emb rows -> bf16 z
__global__ __launch_bounds__(256) void embed_kernel(const int* __restrict__ idx,
                                                    const float* __restrict__ emb,
                                                    u16* __restrict__ z) {
    int u = blockIdx.x * 256 + threadIdx.x;   // one unit = 8 elements
    int t = u >> 6;
    int d0 = (u & 63) * 8;
    int row = idx[t];
    const float4* src = (const float4*)(emb + (size_t)row * 512 + d0);
    float4 a = src[0], b = src[1];
    u16x8 o;
    o[0] = f2b(a.x); o[1] = f2b(a.y); o[2] = f2b(a.z); o[3] = f2b(a.w);
    o[4] = f2b(b.x); o[5] = f2b(b.y); o[6] = f2b(b.z); o[7] = f2b(b.w);
    *(u16x8*)(z + (size_t)t * 512 + d0) = o;
}

// ---------------- bf16 GEMM 256x128, BK=64, 8 waves (round-0 structure)
// + fused score epilogue (atomicAdd into sfull). R7: both wv2t halves staged once
// into Bs rows 0-15 / 16-31; 4 barriers instead of 5.
template <int RELU, int LNT>
__global__ __launch_bounds__(512) void gemm_bt256(const u16* __restrict__ A,
                                                  const u16* __restrict__ Bt,
                                                  const float* __restrict__ bias,
                                                  u16* __restrict__ C,
                                                  const u16* __restrict__ wv2t,
                                                  float* __restrict__ sfull,
                                                  int N, int K) {
    __shared__ __align__(16) u16 As[256 * 64];
    __shared__ __align__(16) u16 Bs[128 * 64];
    const int tid = threadIdx.x;
    const int id = blockIdx.x;
    const int xcd = id & 7, s = id >> 3;
    const int n_idx = s & ((1 << LNT) - 1);
    const int m_idx = xcd + 8 * (s >> LNT);
    const int m0 = m_idx * 256, n0 = n_idx * 128;
    const int lane = tid & 63, quad = lane >> 4, l15 = lane & 15;
    const int wave = tid >> 6, wm = wave >> 1, wn = wave & 1;

    f32x4 acc[4][4] = {};

    const int nK = K >> 6;
    for (int kt = 0; kt < nK; ++kt) {
        __syncthreads();
        const int kb = kt * 64;
        #pragma unroll
        for (int r = 0; r < 4; ++r) {
            int u = tid + r * 512;
            int row = u >> 3;
            int cg = (u & 7) ^ (row & 7);
            const u16* ga = A + (size_t)(m0 + row) * K + kb + cg * 8;
            __builtin_amdgcn_global_load_lds((const __attribute__((address_space(1))) void*)ga,
                                             (__attribute__((address_space(3))) void*)(&As[u * 8]),
                                             16, 0, 0);
        }
        #pragma unroll
        for (int r = 0; r < 2; ++r) {
            int u = tid + r * 512;
            int row = u >> 3;
            int cg = (u & 7) ^ (row & 7);
            const u16* gb = Bt + (size_t)(n0 + row) * K + kb + cg * 8;
            __builtin_amdgcn_global_load_lds((const __attribute__((address_space(1))) void*)gb,
                                             (__attribute__((address_space(3))) void*)(&Bs[u * 8]),
                                             16, 0, 0);
        }
        __syncthreads();
        #pragma unroll
        for (int ks = 0; ks < 2; ++ks) {
            bf16x8_t af[4], bfr[4];
            #pragma unroll
            for (int mt = 0; mt < 4; ++mt) {
                int row = wm * 64 + mt * 16 + l15;
                int g = (ks * 4 + quad) ^ (row & 7);
                af[mt] = *(const bf16x8_t*)&As[row * 64 + g * 8];
            }
            #pragma unroll
            for (int nt = 0; nt < 4; ++nt) {
                int row = wn * 64 + nt * 16 + l15;
                int g = (ks * 4 + quad) ^ (row & 7);
                bfr[nt] = *(const bf16x8_t*)&Bs[row * 64 + g * 8];
            }
            #pragma unroll
            for (int mt = 0; mt < 4; ++mt)
                #pragma unroll
                for (int nt = 0; nt < 4; ++nt)
                    acc[mt][nt] = __builtin_amdgcn_mfma_f32_16x16x32_bf16(af[mt], bfr[nt],
                                                                          acc[mt][nt], 0, 0, 0);
        }
    }

    float bvv[4];
    #pragma unroll
    for (int nt = 0; nt < 4; ++nt) bvv[nt] = bias[n0 + wn * 64 + nt * 16 + l15];
    #pragma unroll
    for (int mt = 0; mt < 4; ++mt)
        #pragma unroll
        for (int nt = 0; nt < 4; ++nt)
            #pragma unroll
            for (int r = 0; r < 4; ++r) {
                int row = m0 + wm * 64 + mt * 16 + quad * 4 + r;
                int col = n0 + wn * 64 + nt * 16 + l15;
                float v = acc[mt][nt][r] + bvv[nt];
                if (RELU) v = fmaxf(v, 0.f);
                C[(size_t)row * N + col] = f2b(v);
            }

    // ---- fused score partials: atomicAdd( C_tile @ wv2t_slice^T ) into sfull[token][h]
    __syncthreads();     // all main-loop LDS reads finished in every wave
    f32x4 accs[2] = {};

    // stage wn==0 C-half into As + BOTH wv2t slices into Bs (rows 0-15 / 16-31)
    if (wn == 0) {
        #pragma unroll
        for (int mt = 0; mt < 4; ++mt)
            #pragma unroll
            for (int nt = 0; nt < 4; ++nt)
                #pragma unroll
                for (int r = 0; r < 4; ++r) {
                    int row = wm * 64 + mt * 16 + quad * 4 + r;
                    int c   = nt * 16 + l15;
                    float v = fmaxf(acc[mt][nt][r] + bvv[nt], 0.f);
                    As[row * 64 + (((c >> 3) ^ (row & 7)) << 3) + (c & 7)] = f2b(v);
                }
    }
    if (tid < 256) {
        int p2 = tid >> 7, t2 = tid & 127;
        int hrow = t2 >> 3, cg = t2 & 7;
        u16x8 v = *(const u16x8*)&wv2t[(size_t)hrow * 2048 + n0 + p2 * 64 + cg * 8];
        *(u16x8*)&Bs[(p2 * 16 + hrow) * 64 + ((cg ^ (hrow & 7)) << 3)] = v;
    }
    __syncthreads();
    // p = 0 MFMA
    #pragma unroll
    for (int m2 = 0; m2 < 2; ++m2) {
        int arow = (wave * 2 + m2) * 16 + l15;
        #pragma unroll
        for (int ks = 0; ks < 2; ++ks) {
            bf16x8_t av = *(const bf16x8_t*)&As[arow * 64 + (((ks * 4 + quad) ^ (arow & 7)) << 3)];
            bf16x8_t bv = *(const bf16x8_t*)&Bs[l15 * 64 + (((ks * 4 + quad) ^ (l15 & 7)) << 3)];
            accs[m2] = __builtin_amdgcn_mfma_f32_16x16x32_bf16(av, bv, accs[m2], 0, 0, 0);
        }
    }
    __syncthreads();
    // stage wn==1 C-half
    if (wn == 1) {
        #pragma unroll
        for (int mt = 0; mt < 4; ++mt)
            #pragma unroll
            for (int nt = 0; nt < 4; ++nt)
                #pragma unroll
                for (int r = 0; r < 4; ++r) {
                    int row = wm * 64 + mt * 16 + quad * 4 + r;
                    int c   = nt * 16 + l15;
                    float v = fmaxf(acc[mt][nt][r] + bvv[nt], 0.f);
                    As[row * 64 + (((c >> 3) ^ (row & 7)) << 3) + (c & 7)] = f2b(v);
                }
    }
    __syncthreads();
    // p = 1 MFMA (Bs rows 16-31)
    #pragma unroll
    for (int m2 = 0; m2 < 2; ++m2) {
        int arow = (wave * 2 + m2) * 16 + l15;
        #pragma unroll
        for (int ks = 0; ks < 2; ++ks) {
            bf16x8_t av = *(const bf16x8_t*)&As[arow * 64 + (((ks * 4 + quad) ^ (arow & 7)) << 3)];
            bf16x8_t bv = *(const bf16x8_t*)&Bs[(16 + l15) * 64 + (((ks * 4 + quad) ^ (l15 & 7)) << 3)];
            accs[m2] = __builtin_amdgcn_mfma_f32_16x16x32_bf16(av, bv, accs[m2], 0, 0, 0);
        }
    }
    if (l15 < 8) {
        #pragma unroll
        for (int m2 = 0; m2 < 2; ++m2)
            #pragma unroll
            for (int r = 0; r < 4; ++r) {
                int row = m0 + (wave * 2 + m2) * 16 + quad * 4 + r;
                atomicAdd(&sfull[(size_t)row * 8 + l15], accs[m2][r]);
            }
    }
}

// ---------------- softmax over full set: s = sfull + ck2; p = softmax_l(s)
__global__ __launch_bounds__(256) void softmax_kernel(const float* __restrict__ sfull,
                                                      const float* __restrict__ ck2,
                                                      float* __restrict__ pfin) {
    __shared__ float ps[1024 * 8];   // 32 KB
    __shared__ float red[32 * 8];
    __shared__ float mh[8], dn[8];
    const int b = blockIdx.x, tid = threadIdx.x;
    for (int i = tid; i < 8192; i += 256) {
        int h = i & 7;
        ps[i] = sfull[(size_t)b * 8192 + i] + ck2[h];
    }
    __syncthreads();
    {
        int slot = tid >> 3, h = tid & 7;
        float m = -1e30f;
        for (int i = 0; i < 32; ++i) m = fmaxf(m, ps[(slot + 32 * i) * 8 + h]);
        red[slot * 8 + h] = m;
    }
    __syncthreads();
    if (tid < 8) {
        float m = -1e30f;
        for (int s2 = 0; s2 < 32; ++s2) m = fmaxf(m, red[s2 * 8 + tid]);
        mh[tid] = m;
    }
    __syncthreads();
    for (int i = tid; i < 8192; i += 256) {
        int h = i & 7;
        ps[i] = __expf(ps[i] - mh[h]);
    }
    __syncthreads();
    {
        int slot = tid >> 3, h = tid & 7;
        float sum = 0.f;
        for (int i = 0; i < 32; ++i) sum += ps[(slot + 32 * i) * 8 + h];
        red[slot * 8 + h] = sum;
    }
    __syncthreads();
    if (tid < 8) {
        float sum = 0.f;
        for (int s2 = 0; s2 < 32; ++s2) sum += red[s2 * 8 + tid];
        dn[tid] = 1.f / sum;
    }
    __syncthreads();
    for (int i = tid; i < 8192; i += 256) {
        int h = i & 7;
        pfin[(size_t)b * 8192 + i] = ps[i] * dn[h];
    }
}

// ---------------- pv: g1[b][h][k] = sum_l p[l][h] * C1[b*1024+l][k]  (one C1 pass)
// R7: no psl LDS staging (pfin is 2 MB, L2-resident, 16-lane broadcast per read)
// -> LDS 16 KB, occupancy up from ~3 to ~5 blocks/CU.
__global__ __launch_bounds__(256) void pv_kernel(const u16* __restrict__ C1,
                                                 const float* __restrict__ pfin,
                                                 float* __restrict__ g1) {
    __shared__ float red[4 * 8 * 128];    // 16 KB
    const int kc = blockIdx.x, b = blockIdx.y, tid = threadIdx.x;
    const int lane = tid & 63, wave = tid >> 6;
    const int colgrp = tid & 15, slot = tid >> 4;   // 16 col-groups x 16 l-slots
    const float* pb = pfin + (size_t)b * 8192;
    const u16* base = C1 + (size_t)(b * 1024 + slot) * 2048 + kc * 128 + colgrp * 8;
    float a[8][8] = {};   // [h][j]
    for (int i = 0; i < 64; ++i) {        // l = slot + 16*i
        int l = slot + 16 * i;
        u16x8 v = *(const u16x8*)(base + (size_t)16 * i * 2048);
        float4 p0 = *(const float4*)&pb[l * 8];
        float4 p1 = *(const float4*)&pb[l * 8 + 4];
        float pv8[8] = {p0.x, p0.y, p0.z, p0.w, p1.x, p1.y, p1.z, p1.w};
        #pragma unroll
        for (int j = 0; j < 8; ++j) {
            float hf = b2f(v[j]);
            #pragma unroll
            for (int h = 0; h < 8; ++h) a[h][j] += pv8[h] * hf;
        }
    }
    // reduce the 4 in-wave slots (lane bits 4-5), then 4 waves via LDS
    #pragma unroll
    for (int h = 0; h < 8; ++h)
        #pragma unroll
        for (int j = 0; j < 8; ++j) {
            a[h][j] += __shfl_xor(a[h][j], 16, 64);
            a[h][j] += __shfl_xor(a[h][j], 32, 64);
        }
    if (lane < 16) {
        #pragma unroll
        for (int h = 0; h < 8; ++h)
            #pragma unroll
            for (int j = 0; j < 8; ++j)
                red[(wave * 8 + h) * 128 + lane * 8 + j] = a[h][j];
    }
    __syncthreads();
    for (int i = tid; i < 1024; i += 256) {
        int h = i >> 7, cj = i & 127;
        float sv = red[(0 * 8 + h) * 128 + cj] + red[(1 * 8 + h) * 128 + cj]
                 + red[(2 * 8 + h) * 128 + cj] + red[(3 * 8 + h) * 128 + cj];
        g1[((size_t)b * 8 + h) * 2048 + kc * 128 + cj] = sv;
    }
}

// ---------------- ctx partials: ctxp = g1 @ WW (kc slice)
__global__ __launch_bounds__(256) void ctx_kernel(const float* __restrict__ g1,
                                                  const float* __restrict__ WW,
                                                  float* __restrict__ ctxp) {
    __shared__ float g1c[8 * 512];
    const int kc = blockIdx.x, b = blockIdx.y, tid = threadIdx.x;
    for (int i = tid; i < 4096; i += 256) {
        int hh = i >> 9, k = i & 511;
        g1c[hh * 512 + k] = g1[((size_t)b * 8 + hh) * 2048 + kc * 512 + k];
    }
    __syncthreads();
    const int e1 = tid, e2 = tid + 256;
    const int h1 = e1 >> 6, h2 = e2 >> 6;
    float a1 = 0.f, a2 = 0.f;
    for (int k = 0; k < 512; k += 4) {
        float4 g1v = *(const float4*)&g1c[h1 * 512 + k];
        float4 g2v = *(const float4*)&g1c[h2 * 512 + k];
        const float* wr = WW + (size_t)(kc * 512 + k) * 512;
        a1 += g1v.x * wr[e1] + g1v.y * wr[512 + e1] + g1v.z * wr[1024 + e1] + g1v.w * wr[1536 + e1];
        a2 += g2v.x * wr[e2] + g2v.y * wr[512 + e2] + g2v.z * wr[1024 + e2] + g2v.w * wr[1536 + e2];
    }
    ctxp[((size_t)b * 4 + kc) * 512 + e1] = a1;
    ctxp[((size_t)b * 4 + kc) * 512 + e2] = a2;
}

// ---------------- per-set: ctx fold + pooled = ctx@Wo + bo; LN -> y  (512 thr, 1 e/thr)
__global__ __launch_bounds__(512) void pool2_kernel(const float* __restrict__ ctxp,
                                                    const float* __restrict__ cvv,
                                                    const float* __restrict__ Wo,
                                                    const float* __restrict__ bo,
                                                    const float* __restrict__ g,
                                                    const float* __restrict__ lb,
                                                    float* __restrict__ y) {
    __shared__ float ctx[512];
    __shared__ float red[16];
    __shared__ float stats[2];
    const int b = blockIdx.x, tid = threadIdx.x;
    {
        float s = cvv[tid];
        #pragma unroll
        for (int kc = 0; kc < 4; ++kc) s += ctxp[((size_t)b * 4 + kc) * 512 + tid];
        ctx[tid] = s;
    }
    __syncthreads();
    float acc = bo[tid];
    for (int ee = 0; ee < 512; ++ee) acc += ctx[ee] * Wo[(size_t)ee * 512 + tid];
    float psum = acc, psq = acc * acc;
    for (int off = 32; off; off >>= 1) { psum += __shfl_xor(psum, off, 64); psq += __shfl_xor(psq, off, 64); }
    const int w = tid >> 6, lane = tid & 63;
    if (lane == 0) { red[w] = psum; red[8 + w] = psq; }
    __syncthreads();
    if (tid == 0) {
        float s = 0.f, q2 = 0.f;
        #pragma unroll
        for (int k = 0; k < 8; ++k) { s += red[k]; q2 += red[8 + k]; }
        float mu = s / 512.f;
        float var = q2 / 512.f - mu * mu;
        stats[0] = mu; stats[1] = 1.f / sqrtf(var + 1e-5f);
    }
    __syncthreads();
    y[(size_t)b * 512 + tid] = (acc - stats[0]) * stats[1] * g[tid] + lb[tid];
}

// ---------------- head MLP layer 1: hid = relu(y@Wh1 + bh1)
__global__ __launch_bounds__(256) void h1_kernel(const float* __restrict__ y,
                                                 const float* __restrict__ Wh1,
                                                 const float* __restrict__ bh1,
                                                 float* __restrict__ hid) {
    __shared__ float ys[512];
    const int b = blockIdx.y, tid = threadIdx.x;
    ys[tid] = y[(size_t)b * 512 + tid];
    ys[tid + 256] = y[(size_t)b * 512 + tid + 256];
    __syncthreads();
    int j = blockIdx.x * 256 + tid;
    float acc = bh1[j];
    for (int dd = 0; dd < 512; ++dd) acc += ys[dd] * Wh1[(size_t)dd * 2048 + j];
    hid[(size_t)b * 2048 + j] = fmaxf(acc, 0.f);
}

// ---------------- head MLP layer 2: logits = hid@Wh2 + bh2
__global__ __launch_bounds__(256) void h2_kernel(const float* __restrict__ hid,
                                                 const float* __restrict__ Wh2,
                                                 const float* __restrict__ bh2,
                                                 float* __restrict__ out) {
    __shared__ float red[4];
    const int b = blockIdx.x, tid = threadIdx.x;
    float s = 0.f;
    for (int j = tid; j < 2048; j += 256) s += hid[(size_t)b * 2048 + j] * Wh2[j];
    for (int off = 32; off; off >>= 1) s += __shfl_xor(s, off, 64);
    const int w = tid >> 6, lane = tid & 63;
    if (lane == 0) red[w] = s;
    __syncthreads();
    if (tid == 0) out[b] = red[0] + red[1] + red[2] + red[3] + bh2[0];
}

extern "C" void kernel_launch(void* const* d_in, const int* in_sizes, int n_in,
                              void* d_out, int out_size, void* d_ws, size_t ws_size,
                              hipStream_t stream) {
    const int*   mut_idx = (const int*)d_in[0];
    const float* emb  = (const float*)d_in[2];
    const float* W1   = (const float*)d_in[3];
    const float* b1   = (const float*)d_in[4];
    const float* W2   = (const float*)d_in[5];
    const float* b2   = (const float*)d_in[6];
    const float* q    = (const float*)d_in[7];
    const float* Wq   = (const float*)d_in[8];
    const float* bq   = (const float*)d_in[9];
    const float* Wk   = (const float*)d_in[10];
    const float* bk   = (const float*)d_in[11];
    const float* Wv   = (const float*)d_in[12];
    const float* bv   = (const float*)d_in[13];
    const float* Wo   = (const float*)d_in[14];
    const float* bo   = (const float*)d_in[15];
    const float* ln_g = (const float*)d_in[16];
    const float* ln_b = (const float*)d_in[17];
    const float* Wh1  = (const float*)d_in[18];
    const float* bh1  = (const float*)d_in[19];
    const float* Wh2  = (const float*)d_in[20];
    const float* bh2  = (const float*)d_in[21];
    float* out = (float*)d_out;

    // workspace layout (256B aligned)
    char* p = (char*)d_ws;
    auto alloc = [&](size_t bytes) {
        char* r = p; p += (bytes + 255) & ~(size_t)255; return r;
    };
    u16*  W1t  = (u16*)alloc((size_t)H_ * D_ * 2);              // 2 MB
    u16*  wv2t = (u16*)alloc((size_t)16 * H_ * 2);              // 64 KB
    float* WW  = (float*)alloc((size_t)H_ * D_ * 4);            // 4 MB
    float* qp  = (float*)alloc(D_ * 4);
    float* wke = (float*)alloc((size_t)D_ * NH_ * 4);
    float* cke = (float*)alloc(NH_ * 4);
    float* ck2 = (float*)alloc(NH_ * 4);
    float* cvv = (float*)alloc(D_ * 4);
    float* sfull = (float*)alloc((size_t)TOT * 8 * 4);          // 2 MB score accumulator
    float* pfin = (float*)alloc((size_t)TOT * 8 * 4);           // 2 MB normalized p
    float* g1   = (float*)alloc((size_t)B_ * 8 * H_ * 4);       // 4 MB
    float* ctxp = (float*)alloc((size_t)B_ * 4 * D_ * 4);       // 512 KB
    float* ybuf = (float*)alloc((size_t)B_ * D_ * 4);
    float* hid  = (float*)alloc((size_t)B_ * H_ * 4);
    u16*  z    = (u16*)alloc((size_t)TOT * D_ * 2);             // 67 MB
    u16*  C1   = (u16*)alloc((size_t)TOT * H_ * 2);             // 268 MB

    // setup / weight folding (+ zero the atomic score accumulator)
    zero_kernel<<<TOT * 8 / 1024, 256, 0, stream>>>(sfull);
    transpose_cvt<<<dim3(H_ / 32, D_ / 32), dim3(32, 8), 0, stream>>>(W1, W1t, D_, H_);
    qp_kernel<<<16, 256, 0, stream>>>(q, Wq, bq, qp);
    wke_kernel<<<16, 256, 0, stream>>>(Wk, bk, qp, wke, cke);
    wv2_kernel<<<64, 256, 0, stream>>>(W2, wke, cke, b2, wv2t, ck2);
    cvv_kernel<<<16, 256, 0, stream>>>(Wv, b2, bv, cvv);
    ww_kernel<<<dim3(8, 32), 256, 0, stream>>>(W2, Wv, WW);

    // phi layer-1 + fused score partials (atomic)
    embed_kernel<<<TOT / 4, 256, 0, stream>>>(mut_idx, emb, z);
    gemm_bt256<1, 4><<<dim3((TOT / 256) * 16), 512, 0, stream>>>(z, W1t, b1, C1, wv2t, sfull, H_, D_);

    // softmax -> single-pass PV -> folded tail
    softmax_kernel<<<B_, 256, 0, stream>>>(sfull, ck2, pfin);
    pv_kernel<<<dim3(16, B_), 256, 0, stream>>>(C1, pfin, g1);
    ctx_kernel<<<dim3(4, B_), 256, 0, stream>>>(g1, WW, ctxp);
    pool2_kernel<<<B_, 512, 0, stream>>>(ctxp, cvv, Wo, bo, ln_g, ln_b, ybuf);
    h1_kernel<<<dim3(H_ / 256, B_), 256, 0, stream>>>(ybuf, Wh1, bh1, hid);
    h2_kernel<<<B_, 256, 0, stream>>>(hid, Wh2, bh2, out);
}